// Round 31
// baseline (447.849 us; speedup 1.0000x reference)
//
#include <hip/hip_runtime.h>
#include <hip/hip_bf16.h>

#define B_ 8
#define L_ 48
#define N_ 207
#define D_ 64
#define KH 8
#define T_ 13          // CP = CUT_SIZE + NO_PROXIES
#define CUTS_ 4
#define ND_ (N_ * D_)        // 13248
#define TND_ (T_ * ND_)      // 172224
#define M_ (B_ * T_ * N_)    // 21528 rows for dense layers
#define GBT_ (4 * B_ * T_)   // 416 generator instances

typedef __attribute__((ext_vector_type(8))) short short8;
typedef __attribute__((ext_vector_type(4))) float f32x4;

__device__ __forceinline__ float sigmoidf_(float x) { return 1.f / (1.f + __expf(-x)); }

__device__ __forceinline__ unsigned short f2bf(float f) {
    __hip_bfloat16 h = __float2bfloat16(f);
    return *reinterpret_cast<unsigned short*>(&h);
}

__global__ void zero_kernel(float* p, int n) {
    int i = blockIdx.x * blockDim.x + threadIdx.x;
    if (i < n) p[i] = 0.f;
}

// ------------------------------------------------- param_gen stage 1: coefs
__global__ void param_coef_kernel(
    const float* __restrict__ h_time, const float* __restrict__ h_space,
    const float* __restrict__ Ttw, const float* __restrict__ Ttb,
    const float* __restrict__ wg_w1, const float* __restrict__ wg_b1,
    const float* __restrict__ wg_w2, const float* __restrict__ wg_b2,
    const float* __restrict__ bg_w1, const float* __restrict__ bg_b1,
    const float* __restrict__ bg_w2, const float* __restrict__ bg_b2,
    float* __restrict__ Coef)
{
    int blk = blockIdx.x;                 // g*(B*T) + b*T + c
    int g = blk / (B_ * T_);
    int rem = blk % (B_ * T_);
    int b = rem / T_, c = rem % T_;
    const float* h = (g < 2) ? h_time : h_space;
    int lane = threadIdx.x;

    __shared__ float mem2[64];
    __shared__ float m1s[64];

    {
        float s = 0.f;
        for (int l = 0; l < L_; ++l)
            s += tanhf(h[(b * L_ + l) * 64 + lane]) * Ttw[(g * T_ + c) * L_ + l];
        mem2[lane] = tanhf(s + Ttb[g * T_ + c]);
    }
    __syncthreads();
    {
        int j = lane & 31;
        bool isW = lane < 32;
        const float* w1 = isW ? wg_w1 : bg_w1;
        const float* b1 = isW ? wg_b1 : bg_b1;
        float s = b1[g * 32 + j];
        #pragma unroll 8
        for (int hh = 0; hh < 64; ++hh) s += mem2[hh] * w1[(g * 32 + j) * 64 + hh];
        m1s[lane] = fmaxf(s, 0.f);
    }
    __syncthreads();
    if (lane < 5 || (lane >= 8 && lane < 13)) {
        bool isW = lane < 5;
        int j = isW ? lane : lane - 8;
        const float* w2 = isW ? wg_w2 : bg_w2;
        const float* b2 = isW ? wg_b2 : bg_b2;
        int base = isW ? 0 : 32;
        float s = b2[g * 5 + j];
        #pragma unroll
        for (int k = 0; k < 32; ++k) s += m1s[base + k] * w2[(g * 5 + j) * 32 + k];
        Coef[blk * 16 + (isW ? j : 8 + j)] = fmaxf(s, 0.f);
    }
}

// ------------------------------------- param_gen stage 2: materialize W / B
#define WTOT (GBT_ * 4096)      // 1,703,936
#define BTOT (GBT_ * 64)        // 26,624
__global__ void param_mat_kernel(
    const float* __restrict__ wg_w3, const float* __restrict__ wg_b3,
    const float* __restrict__ bg_w3, const float* __restrict__ bg_b3,
    const float* __restrict__ Coef,
    float* __restrict__ Wg, float* __restrict__ Bg)
{
    int i = blockIdx.x * blockDim.x + threadIdx.x;
    if (i < WTOT) {
        int idx = i & 4095;              // = d*64+e
        int blk = i >> 12;
        int g = blk / (B_ * T_);
        const float* w3 = &wg_w3[((size_t)g * 4096 + idx) * 5];
        const float* cf = &Coef[blk * 16];
        Wg[i] = wg_b3[g * 4096 + idx]
              + cf[0]*w3[0] + cf[1]*w3[1] + cf[2]*w3[2] + cf[3]*w3[3] + cf[4]*w3[4];
    } else if (i < WTOT + BTOT) {
        int k = i - WTOT;
        int idx = k & 63;
        int blk = k >> 6;
        int g = blk / (B_ * T_);
        const float* w3 = &bg_w3[((size_t)g * 64 + idx) * 5];
        const float* cf = &Coef[blk * 16];
        Bg[k] = bg_b3[g * 64 + idx]
              + cf[8]*w3[0] + cf[9]*w3[1] + cf[10]*w3[2] + cf[11]*w3[3] + cf[12]*w3[4];
    }
}

// ----------------------------------------------- custom linear (MFMA bf16)
#define LCM_ROWS 64
#define XSTR 72
__global__ __launch_bounds__(256) void lincustom_t1_kernel(
    const float* __restrict__ x, const float* __restrict__ proxies,
    const float* __restrict__ out_prev,
    const float* __restrict__ W0, const float* __restrict__ Bi0,
    const float* __restrict__ W1, const float* __restrict__ Bi1,
    float* __restrict__ Y0, float* __restrict__ Y1, int cut_start, int cut_idx)
{
    int bt = blockIdx.x;  // b*T + t
    int b = bt / T_, t = bt % T_;
    int which = blockIdx.z;
    const float* W  = which ? W1 : W0;
    const float* Bi = which ? Bi1 : Bi0;
    float* Y        = which ? Y1 : Y0;

    __shared__ __align__(16) unsigned short wt[64 * XSTR];   // wt[e][k] = Wg[k*64+e]
    __shared__ __align__(16) unsigned short xs[LCM_ROWS * XSTR];
    __shared__ float bb[64];
    int tid = threadIdx.x;
    for (int i = tid; i < 4096; i += 256) {
        int d = i >> 6, e = i & 63;      // Wg layout [d*64+e]: d=in, e=out
        wt[e * XSTR + d] = f2bf(W[(size_t)bt * 4096 + i]);
    }
    int n0 = blockIdx.y * LCM_ROWS;
    if (t == 0) {
        const float* pp = proxies + (size_t)cut_idx * ND_;
        const float* op = out_prev + (size_t)b * ND_;
        for (int i = tid; i < LCM_ROWS * 64; i += 256) {
            int r = i >> 6, d = i & 63;
            int n = n0 + r;
            float xv = (n < N_) ? (pp[n * 64 + d] + op[n * 64 + d]) : 0.f;
            xs[r * XSTR + d] = f2bf(xv);
        }
    } else {
        const float* xb = x + ((size_t)(b * L_ + cut_start + t - 1) * N_) * 64;
        for (int i = tid; i < LCM_ROWS * 64; i += 256) {
            int r = i >> 6, d = i & 63;
            int n = n0 + r;
            float xv = (n < N_) ? xb[n * 64 + d] : 0.f;
            xs[r * XSTR + d] = f2bf(xv);
        }
    }
    if (tid < 64) bb[tid] = Bi[bt * 64 + tid];
    __syncthreads();

    int lane = tid & 63;
    int wv = tid >> 6;          // wave 0..3
    int rowa = lane & 15;
    int kgrp = lane >> 4;
    int rbase = wv * 16;

    f32x4 acc0 = {0,0,0,0}, acc1 = {0,0,0,0}, acc2 = {0,0,0,0}, acc3 = {0,0,0,0};
    #pragma unroll
    for (int ks = 0; ks < 2; ++ks) {
        short8 af = *(const short8*)&xs[(rbase + rowa) * XSTR + ks * 32 + kgrp * 8];
        short8 bf0 = *(const short8*)&wt[(0 * 16 + rowa) * XSTR + ks * 32 + kgrp * 8];
        short8 bf1 = *(const short8*)&wt[(1 * 16 + rowa) * XSTR + ks * 32 + kgrp * 8];
        short8 bf2 = *(const short8*)&wt[(2 * 16 + rowa) * XSTR + ks * 32 + kgrp * 8];
        short8 bf3 = *(const short8*)&wt[(3 * 16 + rowa) * XSTR + ks * 32 + kgrp * 8];
        acc0 = __builtin_amdgcn_mfma_f32_16x16x32_bf16(af, bf0, acc0, 0, 0, 0);
        acc1 = __builtin_amdgcn_mfma_f32_16x16x32_bf16(af, bf1, acc1, 0, 0, 0);
        acc2 = __builtin_amdgcn_mfma_f32_16x16x32_bf16(af, bf2, acc2, 0, 0, 0);
        acc3 = __builtin_amdgcn_mfma_f32_16x16x32_bf16(af, bf3, acc3, 0, 0, 0);
    }
    #pragma unroll
    for (int j = 0; j < 4; ++j) {
        int rc = kgrp * 4 + j;
        int n = n0 + rbase + rc;
        if (n >= N_) continue;
        size_t base = (size_t)bt * ND_ + (size_t)n * 64;
        int col = rowa;
        Y[base + 0 * 16 + col] = acc0[j] + bb[0 * 16 + col];
        Y[base + 1 * 16 + col] = acc1[j] + bb[1 * 16 + col];
        Y[base + 2 * 16 + col] = acc2[j] + bb[2 * 16 + col];
        Y[base + 3 * 16 + col] = acc3[j] + bb[3 * 16 + col];
    }
}

__global__ __launch_bounds__(256) void lincustom_kernel(
    const float* __restrict__ X,
    const float* __restrict__ W0, const float* __restrict__ Bi0,
    const float* __restrict__ W1, const float* __restrict__ Bi1,
    float* __restrict__ Y0, float* __restrict__ Y1)
{
    int bt = blockIdx.x;
    int which = blockIdx.z;
    const float* W  = which ? W1 : W0;
    const float* Bi = which ? Bi1 : Bi0;
    float* Y        = which ? Y1 : Y0;

    __shared__ __align__(16) unsigned short wt[64 * XSTR];
    __shared__ __align__(16) unsigned short xs[LCM_ROWS * XSTR];
    __shared__ float bb[64];
    int tid = threadIdx.x;
    for (int i = tid; i < 4096; i += 256) {
        int d = i >> 6, e = i & 63;      // Wg layout [d*64+e]
        wt[e * XSTR + d] = f2bf(W[(size_t)bt * 4096 + i]);
    }
    int n0 = blockIdx.y * LCM_ROWS;
    const float* xb = X + (size_t)bt * ND_;
    for (int i = tid; i < LCM_ROWS * 64; i += 256) {
        int r = i >> 6, d = i & 63;
        int n = n0 + r;
        float xv = (n < N_) ? xb[n * 64 + d] : 0.f;
        xs[r * XSTR + d] = f2bf(xv);
    }
    if (tid < 64) bb[tid] = Bi[bt * 64 + tid];
    __syncthreads();

    int lane = tid & 63;
    int wv = tid >> 6;
    int rowa = lane & 15;
    int kgrp = lane >> 4;
    int rbase = wv * 16;

    f32x4 acc0 = {0,0,0,0}, acc1 = {0,0,0,0}, acc2 = {0,0,0,0}, acc3 = {0,0,0,0};
    #pragma unroll
    for (int ks = 0; ks < 2; ++ks) {
        short8 af = *(const short8*)&xs[(rbase + rowa) * XSTR + ks * 32 + kgrp * 8];
        short8 bf0 = *(const short8*)&wt[(0 * 16 + rowa) * XSTR + ks * 32 + kgrp * 8];
        short8 bf1 = *(const short8*)&wt[(1 * 16 + rowa) * XSTR + ks * 32 + kgrp * 8];
        short8 bf2 = *(const short8*)&wt[(2 * 16 + rowa) * XSTR + ks * 32 + kgrp * 8];
        short8 bf3 = *(const short8*)&wt[(3 * 16 + rowa) * XSTR + ks * 32 + kgrp * 8];
        acc0 = __builtin_amdgcn_mfma_f32_16x16x32_bf16(af, bf0, acc0, 0, 0, 0);
        acc1 = __builtin_amdgcn_mfma_f32_16x16x32_bf16(af, bf1, acc1, 0, 0, 0);
        acc2 = __builtin_amdgcn_mfma_f32_16x16x32_bf16(af, bf2, acc2, 0, 0, 0);
        acc3 = __builtin_amdgcn_mfma_f32_16x16x32_bf16(af, bf3, acc3, 0, 0, 0);
    }
    #pragma unroll
    for (int j = 0; j < 4; ++j) {
        int rc = kgrp * 4 + j;
        int n = n0 + rbase + rc;
        if (n >= N_) continue;
        size_t base = (size_t)bt * ND_ + (size_t)n * 64;
        int col = rowa;
        Y[base + 0 * 16 + col] = acc0[j] + bb[0 * 16 + col];
        Y[base + 1 * 16 + col] = acc1[j] + bb[1 * 16 + col];
        Y[base + 2 * 16 + col] = acc2[j] + bb[2 * 16 + col];
        Y[base + 3 * 16 + col] = acc3[j] + bb[3 * 16 + col];
    }
}

// ------------------------------------------------------- temporal attention
__global__ void temporal_att_kernel(
    const float* __restrict__ proxies, const float* __restrict__ out_prev,
    const float* __restrict__ klin, const float* __restrict__ vlin,
    const float* __restrict__ rate, float* __restrict__ xatt, int cut_idx)
{
    int i = blockIdx.x * blockDim.x + threadIdx.x;
    if (i >= B_ * N_ * KH * T_) return;
    int r = i % T_;
    int h = (i / T_) % KH;
    int n = (i / (T_ * KH)) % N_;
    int b = i / (T_ * KH * N_);

    float srate = sigmoidf_(rate[0]);
    const float rs8 = 0.35355339059327373f;  // 1/sqrt(8)

    float q[8];
    {
        const float4* pp = (const float4*)(proxies + (size_t)cut_idx * ND_ + n * 64 + h * 8);
        const float4* op = (const float4*)(out_prev + (size_t)b * ND_ + n * 64 + h * 8);
        float4 pa = pp[0], pb = pp[1], oa = op[0], ob = op[1];
        q[0] = pa.x + oa.x; q[1] = pa.y + oa.y; q[2] = pa.z + oa.z; q[3] = pa.w + oa.w;
        q[4] = pb.x + ob.x; q[5] = pb.y + ob.y; q[6] = pb.z + ob.z; q[7] = pb.w + ob.w;
    }

    float dec = (float)(T_ - r);
    float p[T_], sum = 0.f;
    for (int t = 0; t < T_; ++t) {
        const float4* kp = (const float4*)(klin + ((size_t)(b * T_ + t)) * ND_ + n * 64 + h * 8);
        float4 ka = kp[0], kb = kp[1];
        float s = q[0]*ka.x + q[1]*ka.y + q[2]*ka.z + q[3]*ka.w
                + q[4]*kb.x + q[5]*kb.y + q[6]*kb.z + q[7]*kb.w;
        float sa = sigmoidf_(s * rs8);
        float sg = sigmoidf_(sa * srate * dec);
        float at = tanhf(sa / (1.f + sg));
        p[t] = __expf(at);
        sum += p[t];
    }
    float inv = 1.f / sum;
    float acc[8] = {0,0,0,0,0,0,0,0};
    for (int t = 0; t < T_; ++t) {
        float w = p[t] * inv;
        const float4* vp = (const float4*)(vlin + ((size_t)(b * T_ + t)) * ND_ + n * 64 + h * 8);
        float4 va = vp[0], vb = vp[1];
        acc[0] += w * va.x; acc[1] += w * va.y; acc[2] += w * va.z; acc[3] += w * va.w;
        acc[4] += w * vb.x; acc[5] += w * vb.y; acc[6] += w * vb.z; acc[7] += w * vb.w;
    }
    float* op = xatt + ((size_t)(b * T_ + r)) * ND_ + n * 64 + h * 8;
    float4* op4 = (float4*)op;
    op4[0] = make_float4(acc[0], acc[1], acc[2], acc[3]);
    op4[1] = make_float4(acc[4], acc[5], acc[6], acc[7]);
}

// ------------------- fused dense-dense (ta chain, MFMA bf16, 2 phases)
#define DG_ROWS 64
__global__ __launch_bounds__(256) void dense2_ta_kernel(
    const float* __restrict__ X,
    const float* __restrict__ W1, const float* __restrict__ b1,
    const float* __restrict__ W2, const float* __restrict__ b2,
    float* __restrict__ Y, int M)
{
    __shared__ __align__(16) unsigned short wt1[64 * XSTR], wt2[64 * XSTR];
    __shared__ __align__(16) unsigned short xs[DG_ROWS * XSTR];
    __shared__ __align__(16) unsigned short in2[DG_ROWS * XSTR];
    __shared__ float bbs[2][64];
    int tid = threadIdx.x;
    for (int i = tid; i < 4096; i += 256) {
        int e = i >> 6, d = i & 63;      // dense W[e*64+d]: e=out, d=in
        wt1[e * XSTR + d] = f2bf(W1[i]);
        wt2[e * XSTR + d] = f2bf(W2[i]);
    }
    if (tid < 64) { bbs[0][tid] = b1[tid]; bbs[1][tid] = b2[tid]; }
    int row0 = blockIdx.x * DG_ROWS;
    for (int i = tid; i < DG_ROWS * 64; i += 256) {
        int r = i >> 6, d = i & 63;
        int row = row0 + r;
        xs[r * XSTR + d] = f2bf((row < M) ? X[(size_t)row * 64 + d] : 0.f);
    }
    __syncthreads();

    int lane = tid & 63;
    int wv = tid >> 6;
    int rowa = lane & 15;
    int kgrp = lane >> 4;
    int rbase = wv * 16;

    // phase 1: tanh(X*W1.T + b1) -> in2
    {
        f32x4 a0 = {0,0,0,0}, a1 = {0,0,0,0}, a2 = {0,0,0,0}, a3 = {0,0,0,0};
        #pragma unroll
        for (int ks = 0; ks < 2; ++ks) {
            short8 af = *(const short8*)&xs[(rbase + rowa) * XSTR + ks*32 + kgrp*8];
            short8 b0 = *(const short8*)&wt1[(0*16 + rowa) * XSTR + ks*32 + kgrp*8];
            short8 b1f = *(const short8*)&wt1[(1*16 + rowa) * XSTR + ks*32 + kgrp*8];
            short8 b2f = *(const short8*)&wt1[(2*16 + rowa) * XSTR + ks*32 + kgrp*8];
            short8 b3f = *(const short8*)&wt1[(3*16 + rowa) * XSTR + ks*32 + kgrp*8];
            a0 = __builtin_amdgcn_mfma_f32_16x16x32_bf16(af, b0, a0, 0, 0, 0);
            a1 = __builtin_amdgcn_mfma_f32_16x16x32_bf16(af, b1f, a1, 0, 0, 0);
            a2 = __builtin_amdgcn_mfma_f32_16x16x32_bf16(af, b2f, a2, 0, 0, 0);
            a3 = __builtin_amdgcn_mfma_f32_16x16x32_bf16(af, b3f, a3, 0, 0, 0);
        }
        #pragma unroll
        for (int j = 0; j < 4; ++j) {
            int rr = rbase + kgrp * 4 + j;
            in2[rr * XSTR + 0*16 + rowa] = f2bf(tanhf(a0[j] + bbs[0][0*16 + rowa]));
            in2[rr * XSTR + 1*16 + rowa] = f2bf(tanhf(a1[j] + bbs[0][1*16 + rowa]));
            in2[rr * XSTR + 2*16 + rowa] = f2bf(tanhf(a2[j] + bbs[0][2*16 + rowa]));
            in2[rr * XSTR + 3*16 + rowa] = f2bf(tanhf(a3[j] + bbs[0][3*16 + rowa]));
        }
    }
    __syncthreads();

    // phase 2: Y = in2*W2.T + b2 -> fp32 global
    {
        f32x4 a0 = {0,0,0,0}, a1 = {0,0,0,0}, a2 = {0,0,0,0}, a3 = {0,0,0,0};
        #pragma unroll
        for (int ks = 0; ks < 2; ++ks) {
            short8 af = *(const short8*)&in2[(rbase + rowa) * XSTR + ks*32 + kgrp*8];
            short8 b0 = *(const short8*)&wt2[(0*16 + rowa) * XSTR + ks*32 + kgrp*8];
            short8 b1f = *(const short8*)&wt2[(1*16 + rowa) * XSTR + ks*32 + kgrp*8];
            short8 b2f = *(const short8*)&wt2[(2*16 + rowa) * XSTR + ks*32 + kgrp*8];
            short8 b3f = *(const short8*)&wt2[(3*16 + rowa) * XSTR + ks*32 + kgrp*8];
            a0 = __builtin_amdgcn_mfma_f32_16x16x32_bf16(af, b0, a0, 0, 0, 0);
            a1 = __builtin_amdgcn_mfma_f32_16x16x32_bf16(af, b1f, a1, 0, 0, 0);
            a2 = __builtin_amdgcn_mfma_f32_16x16x32_bf16(af, b2f, a2, 0, 0, 0);
            a3 = __builtin_amdgcn_mfma_f32_16x16x32_bf16(af, b3f, a3, 0, 0, 0);
        }
        #pragma unroll
        for (int j = 0; j < 4; ++j) {
            int rr = rbase + kgrp * 4 + j;
            int row = row0 + rr;
            if (row >= M) continue;
            size_t base = (size_t)row * 64;
            Y[base + 0*16 + rowa] = a0[j] + bbs[1][0*16 + rowa];
            Y[base + 1*16 + rowa] = a1[j] + bbs[1][1*16 + rowa];
            Y[base + 2*16 + rowa] = a2[j] + bbs[1][2*16 + rowa];
            Y[base + 3*16 + rowa] = a3[j] + bbs[1][3*16 + rowa];
        }
    }
}

// ------------------------- fused gate chain (4 dense layers, MFMA bf16)
__global__ __launch_bounds__(256) void dense2_gate_kernel(
    const float* __restrict__ X,
    const float* __restrict__ Wsa1, const float* __restrict__ bsa1,
    const float* __restrict__ Wsa2, const float* __restrict__ bsa2,
    const float* __restrict__ Wag1, const float* __restrict__ bag1,
    const float* __restrict__ Wag2, const float* __restrict__ bag2,
    float* __restrict__ OG, int M)
{
    __shared__ __align__(16) unsigned short wt1[64 * XSTR], wt2[64 * XSTR],
                                            wt3[64 * XSTR], wt4[64 * XSTR];
    __shared__ __align__(16) unsigned short xs[DG_ROWS * XSTR];
    __shared__ __align__(16) unsigned short in2[DG_ROWS * XSTR];
    __shared__ float bbs[4][64];
    int tid = threadIdx.x;
    for (int i = tid; i < 4096; i += 256) {
        int e = i >> 6, d = i & 63;      // W[e*64+d]: e=out, d=in
        wt1[e * XSTR + d] = f2bf(Wsa1[i]);
        wt2[e * XSTR + d] = f2bf(Wsa2[i]);
        wt3[e * XSTR + d] = f2bf(Wag1[i]);
        wt4[e * XSTR + d] = f2bf(Wag2[i]);
    }
    if (tid < 64) {
        bbs[0][tid] = bsa1[tid]; bbs[1][tid] = bsa2[tid];
        bbs[2][tid] = bag1[tid]; bbs[3][tid] = bag2[tid];
    }
    int row0 = blockIdx.x * DG_ROWS;
    for (int i = tid; i < DG_ROWS * 64; i += 256) {
        int r = i >> 6, d = i & 63;
        int row = row0 + r;
        xs[r * XSTR + d] = f2bf((row < M) ? X[(size_t)row * 64 + d] : 0.f);
    }
    __syncthreads();

    int lane = tid & 63;
    int wv = tid >> 6;
    int rowa = lane & 15;
    int kgrp = lane >> 4;
    int rbase = wv * 16;

#define DG_PHASE(WT, BIDX, ACTEXPR, DST)                                         \
    {                                                                            \
        f32x4 a0 = {0,0,0,0}, a1 = {0,0,0,0}, a2 = {0,0,0,0}, a3 = {0,0,0,0};    \
        _Pragma("unroll")                                                        \
        for (int ks = 0; ks < 2; ++ks) {                                         \
            short8 af = *(const short8*)&SRC[(rbase + rowa) * XSTR + ks*32 + kgrp*8]; \
            short8 b0 = *(const short8*)&WT[(0*16 + rowa) * XSTR + ks*32 + kgrp*8];   \
            short8 b1 = *(const short8*)&WT[(1*16 + rowa) * XSTR + ks*32 + kgrp*8];   \
            short8 b2 = *(const short8*)&WT[(2*16 + rowa) * XSTR + ks*32 + kgrp*8];   \
            short8 b3 = *(const short8*)&WT[(3*16 + rowa) * XSTR + ks*32 + kgrp*8];   \
            a0 = __builtin_amdgcn_mfma_f32_16x16x32_bf16(af, b0, a0, 0, 0, 0);   \
            a1 = __builtin_amdgcn_mfma_f32_16x16x32_bf16(af, b1, a1, 0, 0, 0);   \
            a2 = __builtin_amdgcn_mfma_f32_16x16x32_bf16(af, b2, a2, 0, 0, 0);   \
            a3 = __builtin_amdgcn_mfma_f32_16x16x32_bf16(af, b3, a3, 0, 0, 0);   \
        }                                                                        \
        _Pragma("unroll")                                                        \
        for (int j = 0; j < 4; ++j) {                                            \
            int rr = rbase + kgrp * 4 + j;                                       \
            float v0 = a0[j] + bbs[BIDX][0*16 + rowa];                           \
            float v1 = a1[j] + bbs[BIDX][1*16 + rowa];                           \
            float v2 = a2[j] + bbs[BIDX][2*16 + rowa];                           \
            float v3 = a3[j] + bbs[BIDX][3*16 + rowa];                           \
            ACTEXPR;                                                             \
            DST[rr * XSTR + 0*16 + rowa] = f2bf(v0);                             \
            DST[rr * XSTR + 1*16 + rowa] = f2bf(v1);                             \
            DST[rr * XSTR + 2*16 + rowa] = f2bf(v2);                             \
            DST[rr * XSTR + 3*16 + rowa] = f2bf(v3);                             \
        }                                                                        \
    }

    // phase 1: relu(X*W1 + b1) -> in2
#define SRC xs
    DG_PHASE(wt1, 0,
        { v0 = fmaxf(v0, 0.f); v1 = fmaxf(v1, 0.f); v2 = fmaxf(v2, 0.f); v3 = fmaxf(v3, 0.f); },
        in2)
#undef SRC
    __syncthreads();

    // phase 2: o = in2*W2 + b2 -> keep fp32 oreg, write bf16 to xs
    float og0[4], og1[4], og2[4], og3[4];
    {
        f32x4 a0 = {0,0,0,0}, a1 = {0,0,0,0}, a2 = {0,0,0,0}, a3 = {0,0,0,0};
        #pragma unroll
        for (int ks = 0; ks < 2; ++ks) {
            short8 af = *(const short8*)&in2[(rbase + rowa) * XSTR + ks*32 + kgrp*8];
            short8 b0 = *(const short8*)&wt2[(0*16 + rowa) * XSTR + ks*32 + kgrp*8];
            short8 b1 = *(const short8*)&wt2[(1*16 + rowa) * XSTR + ks*32 + kgrp*8];
            short8 b2 = *(const short8*)&wt2[(2*16 + rowa) * XSTR + ks*32 + kgrp*8];
            short8 b3 = *(const short8*)&wt2[(3*16 + rowa) * XSTR + ks*32 + kgrp*8];
            a0 = __builtin_amdgcn_mfma_f32_16x16x32_bf16(af, b0, a0, 0, 0, 0);
            a1 = __builtin_amdgcn_mfma_f32_16x16x32_bf16(af, b1, a1, 0, 0, 0);
            a2 = __builtin_amdgcn_mfma_f32_16x16x32_bf16(af, b2, a2, 0, 0, 0);
            a3 = __builtin_amdgcn_mfma_f32_16x16x32_bf16(af, b3, a3, 0, 0, 0);
        }
        __syncthreads();   // all phase-1 reads done before xs overwrite
        #pragma unroll
        for (int j = 0; j < 4; ++j) {
            int rr = rbase + kgrp * 4 + j;
            og0[j] = a0[j] + bbs[1][0*16 + rowa];
            og1[j] = a1[j] + bbs[1][1*16 + rowa];
            og2[j] = a2[j] + bbs[1][2*16 + rowa];
            og3[j] = a3[j] + bbs[1][3*16 + rowa];
            xs[rr * XSTR + 0*16 + rowa] = f2bf(og0[j]);
            xs[rr * XSTR + 1*16 + rowa] = f2bf(og1[j]);
            xs[rr * XSTR + 2*16 + rowa] = f2bf(og2[j]);
            xs[rr * XSTR + 3*16 + rowa] = f2bf(og3[j]);
        }
    }
    __syncthreads();

    // phase 3: relu(o*W3 + b3) -> in2
#define SRC xs
    DG_PHASE(wt3, 2,
        { v0 = fmaxf(v0, 0.f); v1 = fmaxf(v1, 0.f); v2 = fmaxf(v2, 0.f); v3 = fmaxf(v3, 0.f); },
        in2)
#undef SRC
    __syncthreads();

    // phase 4: gate = in2*W4 + b4; og = o * sigmoid(gate) -> global
    {
        f32x4 a0 = {0,0,0,0}, a1 = {0,0,0,0}, a2 = {0,0,0,0}, a3 = {0,0,0,0};
        #pragma unroll
        for (int ks = 0; ks < 2; ++ks) {
            short8 af = *(const short8*)&in2[(rbase + rowa) * XSTR + ks*32 + kgrp*8];
            short8 b0 = *(const short8*)&wt4[(0*16 + rowa) * XSTR + ks*32 + kgrp*8];
            short8 b1 = *(const short8*)&wt4[(1*16 + rowa) * XSTR + ks*32 + kgrp*8];
            short8 b2 = *(const short8*)&wt4[(2*16 + rowa) * XSTR + ks*32 + kgrp*8];
            short8 b3 = *(const short8*)&wt4[(3*16 + rowa) * XSTR + ks*32 + kgrp*8];
            a0 = __builtin_amdgcn_mfma_f32_16x16x32_bf16(af, b0, a0, 0, 0, 0);
            a1 = __builtin_amdgcn_mfma_f32_16x16x32_bf16(af, b1, a1, 0, 0, 0);
            a2 = __builtin_amdgcn_mfma_f32_16x16x32_bf16(af, b2, a2, 0, 0, 0);
            a3 = __builtin_amdgcn_mfma_f32_16x16x32_bf16(af, b3, a3, 0, 0, 0);
        }
        #pragma unroll
        for (int j = 0; j < 4; ++j) {
            int rr = rbase + kgrp * 4 + j;
            int row = row0 + rr;
            if (row >= M) continue;
            size_t base = (size_t)row * 64;
            OG[base + 0*16 + rowa] = og0[j] * sigmoidf_(a0[j] + bbs[3][0*16 + rowa]);
            OG[base + 1*16 + rowa] = og1[j] * sigmoidf_(a1[j] + bbs[3][1*16 + rowa]);
            OG[base + 2*16 + rowa] = og2[j] * sigmoidf_(a2[j] + bbs[3][2*16 + rowa]);
            OG[base + 3*16 + rowa] = og3[j] * sigmoidf_(a3[j] + bbs[3][3*16 + rowa]);
        }
    }
#undef DG_PHASE
}

// -------------------------------------------------------- spatial attention
// Proven form + exact unroll-3 on the key loop (207 = 3*69): clusters LDS
// reads and FMA/exp streams for better dual-issue. fp32 math order per
// iteration unchanged (sequential sum/acc adds preserved).
__global__ void spatial_att_kernel(const float* __restrict__ Yq,
                                   const float* __restrict__ Ks, const float* __restrict__ Vs,
                                   float* __restrict__ Out)
{
    int blk = blockIdx.x;
    int bt = blk % (B_ * T_);
    int h = blk / (B_ * T_);
    __shared__ float4 kl[N_ * 2], vl[N_ * 2];
    int tid = threadIdx.x;
    for (int i = tid; i < N_ * 2; i += blockDim.x) {
        int m = i >> 1, half = i & 1;
        kl[i] = *(const float4*)&Ks[(size_t)bt * ND_ + m * 64 + h * 8 + half * 4];
        vl[i] = *(const float4*)&Vs[(size_t)bt * ND_ + m * 64 + h * 8 + half * 4];
    }
    __syncthreads();
    const float rs8 = 0.35355339059327373f;
    for (int n = tid; n < N_; n += blockDim.x) {
        float q[8];
        const float* qp = Yq + (size_t)bt * ND_ + n * 64 + h * 8;
        #pragma unroll
        for (int j = 0; j < 8; ++j) q[j] = qp[j] * rs8;
        float sum = 0.f;
        float acc[8] = {0,0,0,0,0,0,0,0};
        #pragma unroll 3
        for (int m = 0; m < N_; ++m) {
            float4 ka = kl[2 * m], kb = kl[2 * m + 1];
            float s = q[0]*ka.x + q[1]*ka.y + q[2]*ka.z + q[3]*ka.w
                    + q[4]*kb.x + q[5]*kb.y + q[6]*kb.z + q[7]*kb.w;
            float p = __expf(s);
            sum += p;
            float4 va = vl[2 * m], vb = vl[2 * m + 1];
            acc[0] += p * va.x; acc[1] += p * va.y;
            acc[2] += p * va.z; acc[3] += p * va.w;
            acc[4] += p * vb.x; acc[5] += p * vb.y;
            acc[6] += p * vb.z; acc[7] += p * vb.w;
        }
        float inv = 1.f / sum;
        float* op = Out + (size_t)bt * ND_ + n * 64 + h * 8;
        #pragma unroll
        for (int j = 0; j < 8; ++j) op[j] = acc[j] * inv;
    }
}

// ------------------------------------------------------------- gate reduce
__global__ void gate_reduce_kernel(const float* __restrict__ OG,
                                   float* __restrict__ out_fp32, float* __restrict__ d_out,
                                   int cut_idx)
{
    int i = blockIdx.x * blockDim.x + threadIdx.x;
    if (i >= B_ * ND_) return;
    int b = i / ND_;
    int nd = i % ND_;
    float s = 0.f;
    for (int t = 0; t < T_; ++t)
        s += OG[((size_t)(b * T_ + t)) * ND_ + nd];
    out_fp32[i] = s;
    d_out[((size_t)b * CUTS_ + cut_idx) * ND_ + nd] = s;
}

// ======================================================================
extern "C" void kernel_launch(void* const* d_in, const int* in_sizes, int n_in,
                              void* d_out, int out_size, void* d_ws, size_t ws_size,
                              hipStream_t stream)
{
    const float* x        = (const float*)d_in[0];
    const float* h_time   = (const float*)d_in[1];
    const float* h_space  = (const float*)d_in[2];
    const float* gen_Tt_w = (const float*)d_in[3];
    const float* gen_Tt_b = (const float*)d_in[4];
    const float* wg_w1    = (const float*)d_in[5];
    const float* wg_b1    = (const float*)d_in[6];
    const float* wg_w2    = (const float*)d_in[7];
    const float* wg_b2    = (const float*)d_in[8];
    const float* wg_w3    = (const float*)d_in[9];
    const float* wg_b3    = (const float*)d_in[10];
    const float* bg_w1    = (const float*)d_in[11];
    const float* bg_b1    = (const float*)d_in[12];
    const float* bg_w2    = (const float*)d_in[13];
    const float* bg_b2    = (const float*)d_in[14];
    const float* bg_w3    = (const float*)d_in[15];
    const float* bg_b3    = (const float*)d_in[16];
    const float* proxies  = (const float*)d_in[17];
    const float* ta_p1_w  = (const float*)d_in[18];
    const float* ta_p1_b  = (const float*)d_in[19];
    const float* ta_p2_w  = (const float*)d_in[20];
    const float* ta_p2_b  = (const float*)d_in[21];
    const float* rate     = (const float*)d_in[22];
    const float* sa_p1_w  = (const float*)d_in[23];
    const float* sa_p1_b  = (const float*)d_in[24];
    const float* sa_p2_w  = (const float*)d_in[25];
    const float* sa_p2_b  = (const float*)d_in[26];
    const float* agg_w1   = (const float*)d_in[27];
    const float* agg_b1   = (const float*)d_in[28];
    const float* agg_w2   = (const float*)d_in[29];
    const float* agg_b2   = (const float*)d_in[30];

    float* outp = (float*)d_out;

    float* ws = (float*)d_ws;
    const size_t S = (size_t)B_ * TND_;             // 1,378,944 floats
    const size_t genW = (size_t)B_ * T_ * 4096;
    const size_t genB = (size_t)B_ * T_ * 64;
    size_t off = 0;
    float* Wg   = ws + off; off += 4 * genW;
    float* Bg   = ws + off; off += 4 * genB;
    float* A    = ws + off; off += S;
    float* Bb   = ws + off; off += S;
    float* C    = ws + off; off += S;
    float* Dd   = ws + off; off += S;
    float* out_fp32 = ws + off; off += (size_t)B_ * ND_;
    float* Coef = ws + off; off += GBT_ * 16;

    zero_kernel<<<(B_ * ND_ + 255) / 256, 256, 0, stream>>>(out_fp32, B_ * ND_);

    param_coef_kernel<<<GBT_, 64, 0, stream>>>(
        h_time, h_space, gen_Tt_w, gen_Tt_b,
        wg_w1, wg_b1, wg_w2, wg_b2,
        bg_w1, bg_b1, bg_w2, bg_b2, Coef);
    param_mat_kernel<<<(WTOT + BTOT + 255) / 256, 256, 0, stream>>>(
        wg_w3, wg_b3, bg_w3, bg_b3, Coef, Wg, Bg);

    const int cut_starts[4] = {0, 12, 24, 36};
    const dim3 lcGrid(B_ * T_, (N_ + LCM_ROWS - 1) / LCM_ROWS, 2);  // (104, 4, 2)
    const int dgGrid = (M_ + DG_ROWS - 1) / DG_ROWS;  // 337
    const int taGrid = (B_ * N_ * KH * T_ + 255) / 256;

    for (int cut = 0; cut < CUTS_; ++cut) {
        // temporal k (gen0) -> A, v (gen1) -> Bb, from virtual t1
        lincustom_t1_kernel<<<lcGrid, 256, 0, stream>>>(
            x, proxies, out_fp32,
            Wg + 0 * genW, Bg + 0 * genB, Wg + 1 * genW, Bg + 1 * genB,
            A, Bb, cut_starts[cut], cut);
        // temporal attention -> C
        temporal_att_kernel<<<taGrid, 256, 0, stream>>>(
            proxies, out_fp32, A, Bb, rate, C, cut);
        // y = dense(tanh(dense(xatt, p1)), p2) -> Dd  (MFMA)
        dense2_ta_kernel<<<dgGrid, 256, 0, stream>>>(C, ta_p1_w, ta_p1_b, ta_p2_w, ta_p2_b, Dd, M_);
        // spatial k (gen2) -> A, v (gen3) -> Bb
        lincustom_kernel<<<lcGrid, 256, 0, stream>>>(
            Dd, Wg + 2 * genW, Bg + 2 * genB, Wg + 3 * genW, Bg + 3 * genB, A, Bb);
        // spatial attention (q = Dd) -> C  (fp32, proven)
        spatial_att_kernel<<<B_ * T_ * KH, 256, 0, stream>>>(Dd, A, Bb, C);
        // fused: o = dense2(sa chain), og = o*sigmoid(dense2(agg chain)) -> Dd
        dense2_gate_kernel<<<dgGrid, 256, 0, stream>>>(
            C, sa_p1_w, sa_p1_b, sa_p2_w, sa_p2_b,
            agg_w1, agg_b1, agg_w2, agg_b2, Dd, M_);
        // out = sum_t og
        gate_reduce_kernel<<<(B_ * ND_ + 255) / 256, 256, 0, stream>>>(
            Dd, out_fp32, outp, cut);
    }
}

// Round 32
// 427.810 us; speedup vs baseline: 1.0468x; 1.0468x over previous
//
#include <hip/hip_runtime.h>
#include <hip/hip_bf16.h>

#define B_ 8
#define L_ 48
#define N_ 207
#define D_ 64
#define KH 8
#define T_ 13          // CP = CUT_SIZE + NO_PROXIES
#define CUTS_ 4
#define ND_ (N_ * D_)        // 13248
#define TND_ (T_ * ND_)      // 172224
#define M_ (B_ * T_ * N_)    // 21528 rows for dense layers
#define GBT_ (4 * B_ * T_)   // 416 generator instances

typedef __attribute__((ext_vector_type(8))) short short8;
typedef __attribute__((ext_vector_type(4))) float f32x4;
typedef __attribute__((ext_vector_type(2))) float f32x2;

__device__ __forceinline__ float sigmoidf_(float x) { return 1.f / (1.f + __expf(-x)); }

__device__ __forceinline__ unsigned short f2bf(float f) {
    __hip_bfloat16 h = __float2bfloat16(f);
    return *reinterpret_cast<unsigned short*>(&h);
}

__global__ void zero_kernel(float* p, int n) {
    int i = blockIdx.x * blockDim.x + threadIdx.x;
    if (i < n) p[i] = 0.f;
}

// ------------------------------------------------- param_gen stage 1: coefs
__global__ void param_coef_kernel(
    const float* __restrict__ h_time, const float* __restrict__ h_space,
    const float* __restrict__ Ttw, const float* __restrict__ Ttb,
    const float* __restrict__ wg_w1, const float* __restrict__ wg_b1,
    const float* __restrict__ wg_w2, const float* __restrict__ wg_b2,
    const float* __restrict__ bg_w1, const float* __restrict__ bg_b1,
    const float* __restrict__ bg_w2, const float* __restrict__ bg_b2,
    float* __restrict__ Coef)
{
    int blk = blockIdx.x;                 // g*(B*T) + b*T + c
    int g = blk / (B_ * T_);
    int rem = blk % (B_ * T_);
    int b = rem / T_, c = rem % T_;
    const float* h = (g < 2) ? h_time : h_space;
    int lane = threadIdx.x;

    __shared__ float mem2[64];
    __shared__ float m1s[64];

    {
        float s = 0.f;
        for (int l = 0; l < L_; ++l)
            s += tanhf(h[(b * L_ + l) * 64 + lane]) * Ttw[(g * T_ + c) * L_ + l];
        mem2[lane] = tanhf(s + Ttb[g * T_ + c]);
    }
    __syncthreads();
    {
        int j = lane & 31;
        bool isW = lane < 32;
        const float* w1 = isW ? wg_w1 : bg_w1;
        const float* b1 = isW ? wg_b1 : bg_b1;
        float s = b1[g * 32 + j];
        #pragma unroll 8
        for (int hh = 0; hh < 64; ++hh) s += mem2[hh] * w1[(g * 32 + j) * 64 + hh];
        m1s[lane] = fmaxf(s, 0.f);
    }
    __syncthreads();
    if (lane < 5 || (lane >= 8 && lane < 13)) {
        bool isW = lane < 5;
        int j = isW ? lane : lane - 8;
        const float* w2 = isW ? wg_w2 : bg_w2;
        const float* b2 = isW ? wg_b2 : bg_b2;
        int base = isW ? 0 : 32;
        float s = b2[g * 5 + j];
        #pragma unroll
        for (int k = 0; k < 32; ++k) s += m1s[base + k] * w2[(g * 5 + j) * 32 + k];
        Coef[blk * 16 + (isW ? j : 8 + j)] = fmaxf(s, 0.f);
    }
}

// ------------------------------------- param_gen stage 2: materialize W / B
#define WTOT (GBT_ * 4096)      // 1,703,936
#define BTOT (GBT_ * 64)        // 26,624
__global__ void param_mat_kernel(
    const float* __restrict__ wg_w3, const float* __restrict__ wg_b3,
    const float* __restrict__ bg_w3, const float* __restrict__ bg_b3,
    const float* __restrict__ Coef,
    float* __restrict__ Wg, float* __restrict__ Bg)
{
    int i = blockIdx.x * blockDim.x + threadIdx.x;
    if (i < WTOT) {
        int idx = i & 4095;              // = d*64+e
        int blk = i >> 12;
        int g = blk / (B_ * T_);
        const float* w3 = &wg_w3[((size_t)g * 4096 + idx) * 5];
        const float* cf = &Coef[blk * 16];
        Wg[i] = wg_b3[g * 4096 + idx]
              + cf[0]*w3[0] + cf[1]*w3[1] + cf[2]*w3[2] + cf[3]*w3[3] + cf[4]*w3[4];
    } else if (i < WTOT + BTOT) {
        int k = i - WTOT;
        int idx = k & 63;
        int blk = k >> 6;
        int g = blk / (B_ * T_);
        const float* w3 = &bg_w3[((size_t)g * 64 + idx) * 5];
        const float* cf = &Coef[blk * 16];
        Bg[k] = bg_b3[g * 64 + idx]
              + cf[8]*w3[0] + cf[9]*w3[1] + cf[10]*w3[2] + cf[11]*w3[3] + cf[12]*w3[4];
    }
}

// ----------------------------------------------- custom linear (MFMA bf16)
#define LCM_ROWS 64
#define XSTR 72
__global__ __launch_bounds__(256) void lincustom_t1_kernel(
    const float* __restrict__ x, const float* __restrict__ proxies,
    const float* __restrict__ out_prev,
    const float* __restrict__ W0, const float* __restrict__ Bi0,
    const float* __restrict__ W1, const float* __restrict__ Bi1,
    float* __restrict__ Y0, float* __restrict__ Y1, int cut_start, int cut_idx)
{
    int bt = blockIdx.x;  // b*T + t
    int b = bt / T_, t = bt % T_;
    int which = blockIdx.z;
    const float* W  = which ? W1 : W0;
    const float* Bi = which ? Bi1 : Bi0;
    float* Y        = which ? Y1 : Y0;

    __shared__ __align__(16) unsigned short wt[64 * XSTR];   // wt[e][k] = Wg[k*64+e]
    __shared__ __align__(16) unsigned short xs[LCM_ROWS * XSTR];
    __shared__ float bb[64];
    int tid = threadIdx.x;
    for (int i = tid; i < 4096; i += 256) {
        int d = i >> 6, e = i & 63;      // Wg layout [d*64+e]: d=in, e=out
        wt[e * XSTR + d] = f2bf(W[(size_t)bt * 4096 + i]);
    }
    int n0 = blockIdx.y * LCM_ROWS;
    if (t == 0) {
        const float* pp = proxies + (size_t)cut_idx * ND_;
        const float* op = out_prev + (size_t)b * ND_;
        for (int i = tid; i < LCM_ROWS * 64; i += 256) {
            int r = i >> 6, d = i & 63;
            int n = n0 + r;
            float xv = (n < N_) ? (pp[n * 64 + d] + op[n * 64 + d]) : 0.f;
            xs[r * XSTR + d] = f2bf(xv);
        }
    } else {
        const float* xb = x + ((size_t)(b * L_ + cut_start + t - 1) * N_) * 64;
        for (int i = tid; i < LCM_ROWS * 64; i += 256) {
            int r = i >> 6, d = i & 63;
            int n = n0 + r;
            float xv = (n < N_) ? xb[n * 64 + d] : 0.f;
            xs[r * XSTR + d] = f2bf(xv);
        }
    }
    if (tid < 64) bb[tid] = Bi[bt * 64 + tid];
    __syncthreads();

    int lane = tid & 63;
    int wv = tid >> 6;          // wave 0..3
    int rowa = lane & 15;
    int kgrp = lane >> 4;
    int rbase = wv * 16;

    f32x4 acc0 = {0,0,0,0}, acc1 = {0,0,0,0}, acc2 = {0,0,0,0}, acc3 = {0,0,0,0};
    #pragma unroll
    for (int ks = 0; ks < 2; ++ks) {
        short8 af = *(const short8*)&xs[(rbase + rowa) * XSTR + ks * 32 + kgrp * 8];
        short8 bf0 = *(const short8*)&wt[(0 * 16 + rowa) * XSTR + ks * 32 + kgrp * 8];
        short8 bf1 = *(const short8*)&wt[(1 * 16 + rowa) * XSTR + ks * 32 + kgrp * 8];
        short8 bf2 = *(const short8*)&wt[(2 * 16 + rowa) * XSTR + ks * 32 + kgrp * 8];
        short8 bf3 = *(const short8*)&wt[(3 * 16 + rowa) * XSTR + ks * 32 + kgrp * 8];
        acc0 = __builtin_amdgcn_mfma_f32_16x16x32_bf16(af, bf0, acc0, 0, 0, 0);
        acc1 = __builtin_amdgcn_mfma_f32_16x16x32_bf16(af, bf1, acc1, 0, 0, 0);
        acc2 = __builtin_amdgcn_mfma_f32_16x16x32_bf16(af, bf2, acc2, 0, 0, 0);
        acc3 = __builtin_amdgcn_mfma_f32_16x16x32_bf16(af, bf3, acc3, 0, 0, 0);
    }
    #pragma unroll
    for (int j = 0; j < 4; ++j) {
        int rc = kgrp * 4 + j;
        int n = n0 + rbase + rc;
        if (n >= N_) continue;
        size_t base = (size_t)bt * ND_ + (size_t)n * 64;
        int col = rowa;
        Y[base + 0 * 16 + col] = acc0[j] + bb[0 * 16 + col];
        Y[base + 1 * 16 + col] = acc1[j] + bb[1 * 16 + col];
        Y[base + 2 * 16 + col] = acc2[j] + bb[2 * 16 + col];
        Y[base + 3 * 16 + col] = acc3[j] + bb[3 * 16 + col];
    }
}

__global__ __launch_bounds__(256) void lincustom_kernel(
    const float* __restrict__ X,
    const float* __restrict__ W0, const float* __restrict__ Bi0,
    const float* __restrict__ W1, const float* __restrict__ Bi1,
    float* __restrict__ Y0, float* __restrict__ Y1)
{
    int bt = blockIdx.x;
    int which = blockIdx.z;
    const float* W  = which ? W1 : W0;
    const float* Bi = which ? Bi1 : Bi0;
    float* Y        = which ? Y1 : Y0;

    __shared__ __align__(16) unsigned short wt[64 * XSTR];
    __shared__ __align__(16) unsigned short xs[LCM_ROWS * XSTR];
    __shared__ float bb[64];
    int tid = threadIdx.x;
    for (int i = tid; i < 4096; i += 256) {
        int d = i >> 6, e = i & 63;      // Wg layout [d*64+e]
        wt[e * XSTR + d] = f2bf(W[(size_t)bt * 4096 + i]);
    }
    int n0 = blockIdx.y * LCM_ROWS;
    const float* xb = X + (size_t)bt * ND_;
    for (int i = tid; i < LCM_ROWS * 64; i += 256) {
        int r = i >> 6, d = i & 63;
        int n = n0 + r;
        float xv = (n < N_) ? xb[n * 64 + d] : 0.f;
        xs[r * XSTR + d] = f2bf(xv);
    }
    if (tid < 64) bb[tid] = Bi[bt * 64 + tid];
    __syncthreads();

    int lane = tid & 63;
    int wv = tid >> 6;
    int rowa = lane & 15;
    int kgrp = lane >> 4;
    int rbase = wv * 16;

    f32x4 acc0 = {0,0,0,0}, acc1 = {0,0,0,0}, acc2 = {0,0,0,0}, acc3 = {0,0,0,0};
    #pragma unroll
    for (int ks = 0; ks < 2; ++ks) {
        short8 af = *(const short8*)&xs[(rbase + rowa) * XSTR + ks * 32 + kgrp * 8];
        short8 bf0 = *(const short8*)&wt[(0 * 16 + rowa) * XSTR + ks * 32 + kgrp * 8];
        short8 bf1 = *(const short8*)&wt[(1 * 16 + rowa) * XSTR + ks * 32 + kgrp * 8];
        short8 bf2 = *(const short8*)&wt[(2 * 16 + rowa) * XSTR + ks * 32 + kgrp * 8];
        short8 bf3 = *(const short8*)&wt[(3 * 16 + rowa) * XSTR + ks * 32 + kgrp * 8];
        acc0 = __builtin_amdgcn_mfma_f32_16x16x32_bf16(af, bf0, acc0, 0, 0, 0);
        acc1 = __builtin_amdgcn_mfma_f32_16x16x32_bf16(af, bf1, acc1, 0, 0, 0);
        acc2 = __builtin_amdgcn_mfma_f32_16x16x32_bf16(af, bf2, acc2, 0, 0, 0);
        acc3 = __builtin_amdgcn_mfma_f32_16x16x32_bf16(af, bf3, acc3, 0, 0, 0);
    }
    #pragma unroll
    for (int j = 0; j < 4; ++j) {
        int rc = kgrp * 4 + j;
        int n = n0 + rbase + rc;
        if (n >= N_) continue;
        size_t base = (size_t)bt * ND_ + (size_t)n * 64;
        int col = rowa;
        Y[base + 0 * 16 + col] = acc0[j] + bb[0 * 16 + col];
        Y[base + 1 * 16 + col] = acc1[j] + bb[1 * 16 + col];
        Y[base + 2 * 16 + col] = acc2[j] + bb[2 * 16 + col];
        Y[base + 3 * 16 + col] = acc3[j] + bb[3 * 16 + col];
    }
}

// ------------------------------------------------------- temporal attention
__global__ void temporal_att_kernel(
    const float* __restrict__ proxies, const float* __restrict__ out_prev,
    const float* __restrict__ klin, const float* __restrict__ vlin,
    const float* __restrict__ rate, float* __restrict__ xatt, int cut_idx)
{
    int i = blockIdx.x * blockDim.x + threadIdx.x;
    if (i >= B_ * N_ * KH * T_) return;
    int r = i % T_;
    int h = (i / T_) % KH;
    int n = (i / (T_ * KH)) % N_;
    int b = i / (T_ * KH * N_);

    float srate = sigmoidf_(rate[0]);
    const float rs8 = 0.35355339059327373f;  // 1/sqrt(8)

    float q[8];
    {
        const float4* pp = (const float4*)(proxies + (size_t)cut_idx * ND_ + n * 64 + h * 8);
        const float4* op = (const float4*)(out_prev + (size_t)b * ND_ + n * 64 + h * 8);
        float4 pa = pp[0], pb = pp[1], oa = op[0], ob = op[1];
        q[0] = pa.x + oa.x; q[1] = pa.y + oa.y; q[2] = pa.z + oa.z; q[3] = pa.w + oa.w;
        q[4] = pb.x + ob.x; q[5] = pb.y + ob.y; q[6] = pb.z + ob.z; q[7] = pb.w + ob.w;
    }

    float dec = (float)(T_ - r);
    float p[T_], sum = 0.f;
    for (int t = 0; t < T_; ++t) {
        const float4* kp = (const float4*)(klin + ((size_t)(b * T_ + t)) * ND_ + n * 64 + h * 8);
        float4 ka = kp[0], kb = kp[1];
        float s = q[0]*ka.x + q[1]*ka.y + q[2]*ka.z + q[3]*ka.w
                + q[4]*kb.x + q[5]*kb.y + q[6]*kb.z + q[7]*kb.w;
        float sa = sigmoidf_(s * rs8);
        float sg = sigmoidf_(sa * srate * dec);
        float at = tanhf(sa / (1.f + sg));
        p[t] = __expf(at);
        sum += p[t];
    }
    float inv = 1.f / sum;
    float acc[8] = {0,0,0,0,0,0,0,0};
    for (int t = 0; t < T_; ++t) {
        float w = p[t] * inv;
        const float4* vp = (const float4*)(vlin + ((size_t)(b * T_ + t)) * ND_ + n * 64 + h * 8);
        float4 va = vp[0], vb = vp[1];
        acc[0] += w * va.x; acc[1] += w * va.y; acc[2] += w * va.z; acc[3] += w * va.w;
        acc[4] += w * vb.x; acc[5] += w * vb.y; acc[6] += w * vb.z; acc[7] += w * vb.w;
    }
    float* op = xatt + ((size_t)(b * T_ + r)) * ND_ + n * 64 + h * 8;
    float4* op4 = (float4*)op;
    op4[0] = make_float4(acc[0], acc[1], acc[2], acc[3]);
    op4[1] = make_float4(acc[4], acc[5], acc[6], acc[7]);
}

// ------------------- fused dense-dense (ta chain, MFMA bf16, 2 phases)
#define DG_ROWS 64
__global__ __launch_bounds__(256) void dense2_ta_kernel(
    const float* __restrict__ X,
    const float* __restrict__ W1, const float* __restrict__ b1,
    const float* __restrict__ W2, const float* __restrict__ b2,
    float* __restrict__ Y, int M)
{
    __shared__ __align__(16) unsigned short wt1[64 * XSTR], wt2[64 * XSTR];
    __shared__ __align__(16) unsigned short xs[DG_ROWS * XSTR];
    __shared__ __align__(16) unsigned short in2[DG_ROWS * XSTR];
    __shared__ float bbs[2][64];
    int tid = threadIdx.x;
    for (int i = tid; i < 4096; i += 256) {
        int e = i >> 6, d = i & 63;      // dense W[e*64+d]: e=out, d=in
        wt1[e * XSTR + d] = f2bf(W1[i]);
        wt2[e * XSTR + d] = f2bf(W2[i]);
    }
    if (tid < 64) { bbs[0][tid] = b1[tid]; bbs[1][tid] = b2[tid]; }
    int row0 = blockIdx.x * DG_ROWS;
    for (int i = tid; i < DG_ROWS * 64; i += 256) {
        int r = i >> 6, d = i & 63;
        int row = row0 + r;
        xs[r * XSTR + d] = f2bf((row < M) ? X[(size_t)row * 64 + d] : 0.f);
    }
    __syncthreads();

    int lane = tid & 63;
    int wv = tid >> 6;
    int rowa = lane & 15;
    int kgrp = lane >> 4;
    int rbase = wv * 16;

    // phase 1: tanh(X*W1.T + b1) -> in2
    {
        f32x4 a0 = {0,0,0,0}, a1 = {0,0,0,0}, a2 = {0,0,0,0}, a3 = {0,0,0,0};
        #pragma unroll
        for (int ks = 0; ks < 2; ++ks) {
            short8 af = *(const short8*)&xs[(rbase + rowa) * XSTR + ks*32 + kgrp*8];
            short8 b0 = *(const short8*)&wt1[(0*16 + rowa) * XSTR + ks*32 + kgrp*8];
            short8 b1f = *(const short8*)&wt1[(1*16 + rowa) * XSTR + ks*32 + kgrp*8];
            short8 b2f = *(const short8*)&wt1[(2*16 + rowa) * XSTR + ks*32 + kgrp*8];
            short8 b3f = *(const short8*)&wt1[(3*16 + rowa) * XSTR + ks*32 + kgrp*8];
            a0 = __builtin_amdgcn_mfma_f32_16x16x32_bf16(af, b0, a0, 0, 0, 0);
            a1 = __builtin_amdgcn_mfma_f32_16x16x32_bf16(af, b1f, a1, 0, 0, 0);
            a2 = __builtin_amdgcn_mfma_f32_16x16x32_bf16(af, b2f, a2, 0, 0, 0);
            a3 = __builtin_amdgcn_mfma_f32_16x16x32_bf16(af, b3f, a3, 0, 0, 0);
        }
        #pragma unroll
        for (int j = 0; j < 4; ++j) {
            int rr = rbase + kgrp * 4 + j;
            in2[rr * XSTR + 0*16 + rowa] = f2bf(tanhf(a0[j] + bbs[0][0*16 + rowa]));
            in2[rr * XSTR + 1*16 + rowa] = f2bf(tanhf(a1[j] + bbs[0][1*16 + rowa]));
            in2[rr * XSTR + 2*16 + rowa] = f2bf(tanhf(a2[j] + bbs[0][2*16 + rowa]));
            in2[rr * XSTR + 3*16 + rowa] = f2bf(tanhf(a3[j] + bbs[0][3*16 + rowa]));
        }
    }
    __syncthreads();

    // phase 2: Y = in2*W2.T + b2 -> fp32 global
    {
        f32x4 a0 = {0,0,0,0}, a1 = {0,0,0,0}, a2 = {0,0,0,0}, a3 = {0,0,0,0};
        #pragma unroll
        for (int ks = 0; ks < 2; ++ks) {
            short8 af = *(const short8*)&in2[(rbase + rowa) * XSTR + ks*32 + kgrp*8];
            short8 b0 = *(const short8*)&wt2[(0*16 + rowa) * XSTR + ks*32 + kgrp*8];
            short8 b1f = *(const short8*)&wt2[(1*16 + rowa) * XSTR + ks*32 + kgrp*8];
            short8 b2f = *(const short8*)&wt2[(2*16 + rowa) * XSTR + ks*32 + kgrp*8];
            short8 b3f = *(const short8*)&wt2[(3*16 + rowa) * XSTR + ks*32 + kgrp*8];
            a0 = __builtin_amdgcn_mfma_f32_16x16x32_bf16(af, b0, a0, 0, 0, 0);
            a1 = __builtin_amdgcn_mfma_f32_16x16x32_bf16(af, b1f, a1, 0, 0, 0);
            a2 = __builtin_amdgcn_mfma_f32_16x16x32_bf16(af, b2f, a2, 0, 0, 0);
            a3 = __builtin_amdgcn_mfma_f32_16x16x32_bf16(af, b3f, a3, 0, 0, 0);
        }
        #pragma unroll
        for (int j = 0; j < 4; ++j) {
            int rr = rbase + kgrp * 4 + j;
            int row = row0 + rr;
            if (row >= M) continue;
            size_t base = (size_t)row * 64;
            Y[base + 0*16 + rowa] = a0[j] + bbs[1][0*16 + rowa];
            Y[base + 1*16 + rowa] = a1[j] + bbs[1][1*16 + rowa];
            Y[base + 2*16 + rowa] = a2[j] + bbs[1][2*16 + rowa];
            Y[base + 3*16 + rowa] = a3[j] + bbs[1][3*16 + rowa];
        }
    }
}

// ------------------------- fused gate chain (4 dense layers, MFMA bf16)
__global__ __launch_bounds__(256) void dense2_gate_kernel(
    const float* __restrict__ X,
    const float* __restrict__ Wsa1, const float* __restrict__ bsa1,
    const float* __restrict__ Wsa2, const float* __restrict__ bsa2,
    const float* __restrict__ Wag1, const float* __restrict__ bag1,
    const float* __restrict__ Wag2, const float* __restrict__ bag2,
    float* __restrict__ OG, int M)
{
    __shared__ __align__(16) unsigned short wt1[64 * XSTR], wt2[64 * XSTR],
                                            wt3[64 * XSTR], wt4[64 * XSTR];
    __shared__ __align__(16) unsigned short xs[DG_ROWS * XSTR];
    __shared__ __align__(16) unsigned short in2[DG_ROWS * XSTR];
    __shared__ float bbs[4][64];
    int tid = threadIdx.x;
    for (int i = tid; i < 4096; i += 256) {
        int e = i >> 6, d = i & 63;      // W[e*64+d]: e=out, d=in
        wt1[e * XSTR + d] = f2bf(Wsa1[i]);
        wt2[e * XSTR + d] = f2bf(Wsa2[i]);
        wt3[e * XSTR + d] = f2bf(Wag1[i]);
        wt4[e * XSTR + d] = f2bf(Wag2[i]);
    }
    if (tid < 64) {
        bbs[0][tid] = bsa1[tid]; bbs[1][tid] = bsa2[tid];
        bbs[2][tid] = bag1[tid]; bbs[3][tid] = bag2[tid];
    }
    int row0 = blockIdx.x * DG_ROWS;
    for (int i = tid; i < DG_ROWS * 64; i += 256) {
        int r = i >> 6, d = i & 63;
        int row = row0 + r;
        xs[r * XSTR + d] = f2bf((row < M) ? X[(size_t)row * 64 + d] : 0.f);
    }
    __syncthreads();

    int lane = tid & 63;
    int wv = tid >> 6;
    int rowa = lane & 15;
    int kgrp = lane >> 4;
    int rbase = wv * 16;

#define DG_PHASE(WT, BIDX, ACTEXPR, DST)                                         \
    {                                                                            \
        f32x4 a0 = {0,0,0,0}, a1 = {0,0,0,0}, a2 = {0,0,0,0}, a3 = {0,0,0,0};    \
        _Pragma("unroll")                                                        \
        for (int ks = 0; ks < 2; ++ks) {                                         \
            short8 af = *(const short8*)&SRC[(rbase + rowa) * XSTR + ks*32 + kgrp*8]; \
            short8 b0 = *(const short8*)&WT[(0*16 + rowa) * XSTR + ks*32 + kgrp*8];   \
            short8 b1 = *(const short8*)&WT[(1*16 + rowa) * XSTR + ks*32 + kgrp*8];   \
            short8 b2 = *(const short8*)&WT[(2*16 + rowa) * XSTR + ks*32 + kgrp*8];   \
            short8 b3 = *(const short8*)&WT[(3*16 + rowa) * XSTR + ks*32 + kgrp*8];   \
            a0 = __builtin_amdgcn_mfma_f32_16x16x32_bf16(af, b0, a0, 0, 0, 0);   \
            a1 = __builtin_amdgcn_mfma_f32_16x16x32_bf16(af, b1, a1, 0, 0, 0);   \
            a2 = __builtin_amdgcn_mfma_f32_16x16x32_bf16(af, b2, a2, 0, 0, 0);   \
            a3 = __builtin_amdgcn_mfma_f32_16x16x32_bf16(af, b3, a3, 0, 0, 0);   \
        }                                                                        \
        _Pragma("unroll")                                                        \
        for (int j = 0; j < 4; ++j) {                                            \
            int rr = rbase + kgrp * 4 + j;                                       \
            float v0 = a0[j] + bbs[BIDX][0*16 + rowa];                           \
            float v1 = a1[j] + bbs[BIDX][1*16 + rowa];                           \
            float v2 = a2[j] + bbs[BIDX][2*16 + rowa];                           \
            float v3 = a3[j] + bbs[BIDX][3*16 + rowa];                           \
            ACTEXPR;                                                             \
            DST[rr * XSTR + 0*16 + rowa] = f2bf(v0);                             \
            DST[rr * XSTR + 1*16 + rowa] = f2bf(v1);                             \
            DST[rr * XSTR + 2*16 + rowa] = f2bf(v2);                             \
            DST[rr * XSTR + 3*16 + rowa] = f2bf(v3);                             \
        }                                                                        \
    }

    // phase 1: relu(X*W1 + b1) -> in2
#define SRC xs
    DG_PHASE(wt1, 0,
        { v0 = fmaxf(v0, 0.f); v1 = fmaxf(v1, 0.f); v2 = fmaxf(v2, 0.f); v3 = fmaxf(v3, 0.f); },
        in2)
#undef SRC
    __syncthreads();

    // phase 2: o = in2*W2 + b2 -> keep fp32 oreg, write bf16 to xs
    float og0[4], og1[4], og2[4], og3[4];
    {
        f32x4 a0 = {0,0,0,0}, a1 = {0,0,0,0}, a2 = {0,0,0,0}, a3 = {0,0,0,0};
        #pragma unroll
        for (int ks = 0; ks < 2; ++ks) {
            short8 af = *(const short8*)&in2[(rbase + rowa) * XSTR + ks*32 + kgrp*8];
            short8 b0 = *(const short8*)&wt2[(0*16 + rowa) * XSTR + ks*32 + kgrp*8];
            short8 b1 = *(const short8*)&wt2[(1*16 + rowa) * XSTR + ks*32 + kgrp*8];
            short8 b2 = *(const short8*)&wt2[(2*16 + rowa) * XSTR + ks*32 + kgrp*8];
            short8 b3 = *(const short8*)&wt2[(3*16 + rowa) * XSTR + ks*32 + kgrp*8];
            a0 = __builtin_amdgcn_mfma_f32_16x16x32_bf16(af, b0, a0, 0, 0, 0);
            a1 = __builtin_amdgcn_mfma_f32_16x16x32_bf16(af, b1, a1, 0, 0, 0);
            a2 = __builtin_amdgcn_mfma_f32_16x16x32_bf16(af, b2, a2, 0, 0, 0);
            a3 = __builtin_amdgcn_mfma_f32_16x16x32_bf16(af, b3, a3, 0, 0, 0);
        }
        __syncthreads();   // all phase-1 reads done before xs overwrite
        #pragma unroll
        for (int j = 0; j < 4; ++j) {
            int rr = rbase + kgrp * 4 + j;
            og0[j] = a0[j] + bbs[1][0*16 + rowa];
            og1[j] = a1[j] + bbs[1][1*16 + rowa];
            og2[j] = a2[j] + bbs[1][2*16 + rowa];
            og3[j] = a3[j] + bbs[1][3*16 + rowa];
            xs[rr * XSTR + 0*16 + rowa] = f2bf(og0[j]);
            xs[rr * XSTR + 1*16 + rowa] = f2bf(og1[j]);
            xs[rr * XSTR + 2*16 + rowa] = f2bf(og2[j]);
            xs[rr * XSTR + 3*16 + rowa] = f2bf(og3[j]);
        }
    }
    __syncthreads();

    // phase 3: relu(o*W3 + b3) -> in2
#define SRC xs
    DG_PHASE(wt3, 2,
        { v0 = fmaxf(v0, 0.f); v1 = fmaxf(v1, 0.f); v2 = fmaxf(v2, 0.f); v3 = fmaxf(v3, 0.f); },
        in2)
#undef SRC
    __syncthreads();

    // phase 4: gate = in2*W4 + b4; og = o * sigmoid(gate) -> global
    {
        f32x4 a0 = {0,0,0,0}, a1 = {0,0,0,0}, a2 = {0,0,0,0}, a3 = {0,0,0,0};
        #pragma unroll
        for (int ks = 0; ks < 2; ++ks) {
            short8 af = *(const short8*)&in2[(rbase + rowa) * XSTR + ks*32 + kgrp*8];
            short8 b0 = *(const short8*)&wt4[(0*16 + rowa) * XSTR + ks*32 + kgrp*8];
            short8 b1 = *(const short8*)&wt4[(1*16 + rowa) * XSTR + ks*32 + kgrp*8];
            short8 b2 = *(const short8*)&wt4[(2*16 + rowa) * XSTR + ks*32 + kgrp*8];
            short8 b3 = *(const short8*)&wt4[(3*16 + rowa) * XSTR + ks*32 + kgrp*8];
            a0 = __builtin_amdgcn_mfma_f32_16x16x32_bf16(af, b0, a0, 0, 0, 0);
            a1 = __builtin_amdgcn_mfma_f32_16x16x32_bf16(af, b1, a1, 0, 0, 0);
            a2 = __builtin_amdgcn_mfma_f32_16x16x32_bf16(af, b2, a2, 0, 0, 0);
            a3 = __builtin_amdgcn_mfma_f32_16x16x32_bf16(af, b3, a3, 0, 0, 0);
        }
        #pragma unroll
        for (int j = 0; j < 4; ++j) {
            int rr = rbase + kgrp * 4 + j;
            int row = row0 + rr;
            if (row >= M) continue;
            size_t base = (size_t)row * 64;
            OG[base + 0*16 + rowa] = og0[j] * sigmoidf_(a0[j] + bbs[3][0*16 + rowa]);
            OG[base + 1*16 + rowa] = og1[j] * sigmoidf_(a1[j] + bbs[3][1*16 + rowa]);
            OG[base + 2*16 + rowa] = og2[j] * sigmoidf_(a2[j] + bbs[3][2*16 + rowa]);
            OG[base + 3*16 + rowa] = og3[j] * sigmoidf_(a3[j] + bbs[3][3*16 + rowa]);
        }
    }
#undef DG_PHASE
}

// -------------------------------------------------------- spatial attention
// Proven structure; inner math rewritten on float2 ext-vectors to invite
// v_pk_fma_f32 (packed 2xfp32 FMA) codegen: ~26 -> ~13 VALU issue slots/key.
// Per-lane fp32 IEEE math unchanged; only the score dot-product association
// differs (pairwise lanes then horizontal add) — ~1e-7 relative.
__global__ void spatial_att_kernel(const float* __restrict__ Yq,
                                   const float* __restrict__ Ks, const float* __restrict__ Vs,
                                   float* __restrict__ Out)
{
    int blk = blockIdx.x;
    int bt = blk % (B_ * T_);
    int h = blk / (B_ * T_);
    __shared__ float4 kl[N_ * 2], vl[N_ * 2];
    int tid = threadIdx.x;
    for (int i = tid; i < N_ * 2; i += blockDim.x) {
        int m = i >> 1, half = i & 1;
        kl[i] = *(const float4*)&Ks[(size_t)bt * ND_ + m * 64 + h * 8 + half * 4];
        vl[i] = *(const float4*)&Vs[(size_t)bt * ND_ + m * 64 + h * 8 + half * 4];
    }
    __syncthreads();
    const float rs8 = 0.35355339059327373f;
    for (int n = tid; n < N_; n += blockDim.x) {
        f32x2 q2[4];
        const float* qp = Yq + (size_t)bt * ND_ + n * 64 + h * 8;
        #pragma unroll
        for (int j = 0; j < 4; ++j) {
            q2[j][0] = qp[2 * j] * rs8;
            q2[j][1] = qp[2 * j + 1] * rs8;
        }
        float sum = 0.f;
        f32x2 acc2[4] = {{0,0},{0,0},{0,0},{0,0}};
        for (int m = 0; m < N_; ++m) {
            float4 ka = kl[2 * m], kb = kl[2 * m + 1];
            f32x2 s2 = q2[0] * (f32x2){ka.x, ka.y};
            s2 += q2[1] * (f32x2){ka.z, ka.w};
            s2 += q2[2] * (f32x2){kb.x, kb.y};
            s2 += q2[3] * (f32x2){kb.z, kb.w};
            float p = __expf(s2[0] + s2[1]);
            sum += p;
            f32x2 p2 = {p, p};
            float4 va = vl[2 * m], vb = vl[2 * m + 1];
            acc2[0] += p2 * (f32x2){va.x, va.y};
            acc2[1] += p2 * (f32x2){va.z, va.w};
            acc2[2] += p2 * (f32x2){vb.x, vb.y};
            acc2[3] += p2 * (f32x2){vb.z, vb.w};
        }
        float inv = 1.f / sum;
        float* op = Out + (size_t)bt * ND_ + n * 64 + h * 8;
        #pragma unroll
        for (int j = 0; j < 4; ++j) {
            op[2 * j]     = acc2[j][0] * inv;
            op[2 * j + 1] = acc2[j][1] * inv;
        }
    }
}

// ------------------------------------------------------------- gate reduce
__global__ void gate_reduce_kernel(const float* __restrict__ OG,
                                   float* __restrict__ out_fp32, float* __restrict__ d_out,
                                   int cut_idx)
{
    int i = blockIdx.x * blockDim.x + threadIdx.x;
    if (i >= B_ * ND_) return;
    int b = i / ND_;
    int nd = i % ND_;
    float s = 0.f;
    for (int t = 0; t < T_; ++t)
        s += OG[((size_t)(b * T_ + t)) * ND_ + nd];
    out_fp32[i] = s;
    d_out[((size_t)b * CUTS_ + cut_idx) * ND_ + nd] = s;
}

// ======================================================================
extern "C" void kernel_launch(void* const* d_in, const int* in_sizes, int n_in,
                              void* d_out, int out_size, void* d_ws, size_t ws_size,
                              hipStream_t stream)
{
    const float* x        = (const float*)d_in[0];
    const float* h_time   = (const float*)d_in[1];
    const float* h_space  = (const float*)d_in[2];
    const float* gen_Tt_w = (const float*)d_in[3];
    const float* gen_Tt_b = (const float*)d_in[4];
    const float* wg_w1    = (const float*)d_in[5];
    const float* wg_b1    = (const float*)d_in[6];
    const float* wg_w2    = (const float*)d_in[7];
    const float* wg_b2    = (const float*)d_in[8];
    const float* wg_w3    = (const float*)d_in[9];
    const float* wg_b3    = (const float*)d_in[10];
    const float* bg_w1    = (const float*)d_in[11];
    const float* bg_b1    = (const float*)d_in[12];
    const float* bg_w2    = (const float*)d_in[13];
    const float* bg_b2    = (const float*)d_in[14];
    const float* bg_w3    = (const float*)d_in[15];
    const float* bg_b3    = (const float*)d_in[16];
    const float* proxies  = (const float*)d_in[17];
    const float* ta_p1_w  = (const float*)d_in[18];
    const float* ta_p1_b  = (const float*)d_in[19];
    const float* ta_p2_w  = (const float*)d_in[20];
    const float* ta_p2_b  = (const float*)d_in[21];
    const float* rate     = (const float*)d_in[22];
    const float* sa_p1_w  = (const float*)d_in[23];
    const float* sa_p1_b  = (const float*)d_in[24];
    const float* sa_p2_w  = (const float*)d_in[25];
    const float* sa_p2_b  = (const float*)d_in[26];
    const float* agg_w1   = (const float*)d_in[27];
    const float* agg_b1   = (const float*)d_in[28];
    const float* agg_w2   = (const float*)d_in[29];
    const float* agg_b2   = (const float*)d_in[30];

    float* outp = (float*)d_out;

    float* ws = (float*)d_ws;
    const size_t S = (size_t)B_ * TND_;             // 1,378,944 floats
    const size_t genW = (size_t)B_ * T_ * 4096;
    const size_t genB = (size_t)B_ * T_ * 64;
    size_t off = 0;
    float* Wg   = ws + off; off += 4 * genW;
    float* Bg   = ws + off; off += 4 * genB;
    float* A    = ws + off; off += S;
    float* Bb   = ws + off; off += S;
    float* C    = ws + off; off += S;
    float* Dd   = ws + off; off += S;
    float* out_fp32 = ws + off; off += (size_t)B_ * ND_;
    float* Coef = ws + off; off += GBT_ * 16;

    zero_kernel<<<(B_ * ND_ + 255) / 256, 256, 0, stream>>>(out_fp32, B_ * ND_);

    param_coef_kernel<<<GBT_, 64, 0, stream>>>(
        h_time, h_space, gen_Tt_w, gen_Tt_b,
        wg_w1, wg_b1, wg_w2, wg_b2,
        bg_w1, bg_b1, bg_w2, bg_b2, Coef);
    param_mat_kernel<<<(WTOT + BTOT + 255) / 256, 256, 0, stream>>>(
        wg_w3, wg_b3, bg_w3, bg_b3, Coef, Wg, Bg);

    const int cut_starts[4] = {0, 12, 24, 36};
    const dim3 lcGrid(B_ * T_, (N_ + LCM_ROWS - 1) / LCM_ROWS, 2);  // (104, 4, 2)
    const int dgGrid = (M_ + DG_ROWS - 1) / DG_ROWS;  // 337
    const int taGrid = (B_ * N_ * KH * T_ + 255) / 256;

    for (int cut = 0; cut < CUTS_; ++cut) {
        // temporal k (gen0) -> A, v (gen1) -> Bb, from virtual t1
        lincustom_t1_kernel<<<lcGrid, 256, 0, stream>>>(
            x, proxies, out_fp32,
            Wg + 0 * genW, Bg + 0 * genB, Wg + 1 * genW, Bg + 1 * genB,
            A, Bb, cut_starts[cut], cut);
        // temporal attention -> C
        temporal_att_kernel<<<taGrid, 256, 0, stream>>>(
            proxies, out_fp32, A, Bb, rate, C, cut);
        // y = dense(tanh(dense(xatt, p1)), p2) -> Dd  (MFMA)
        dense2_ta_kernel<<<dgGrid, 256, 0, stream>>>(C, ta_p1_w, ta_p1_b, ta_p2_w, ta_p2_b, Dd, M_);
        // spatial k (gen2) -> A, v (gen3) -> Bb
        lincustom_kernel<<<lcGrid, 256, 0, stream>>>(
            Dd, Wg + 2 * genW, Bg + 2 * genB, Wg + 3 * genW, Bg + 3 * genB, A, Bb);
        // spatial attention (q = Dd) -> C  (fp32, packed-math)
        spatial_att_kernel<<<B_ * T_ * KH, 256, 0, stream>>>(Dd, A, Bb, C);
        // fused: o = dense2(sa chain), og = o*sigmoid(dense2(agg chain)) -> Dd
        dense2_gate_kernel<<<dgGrid, 256, 0, stream>>>(
            C, sa_p1_w, sa_p1_b, sa_p2_w, sa_p2_b,
            agg_w1, agg_b1, agg_w2, agg_b2, Dd, M_);
        // out = sum_t og
        gate_reduce_kernel<<<(B_ * ND_ + 255) / 256, 256, 0, stream>>>(
            Dd, out_fp32, outp, cut);
    }
}

// Round 33
// 424.731 us; speedup vs baseline: 1.0544x; 1.0072x over previous
//
#include <hip/hip_runtime.h>
#include <hip/hip_bf16.h>

#define B_ 8
#define L_ 48
#define N_ 207
#define D_ 64
#define KH 8
#define T_ 13          // CP = CUT_SIZE + NO_PROXIES
#define CUTS_ 4
#define ND_ (N_ * D_)        // 13248
#define TND_ (T_ * ND_)      // 172224
#define M_ (B_ * T_ * N_)    // 21528 rows for dense layers
#define GBT_ (4 * B_ * T_)   // 416 generator instances

typedef __attribute__((ext_vector_type(8))) short short8;
typedef __attribute__((ext_vector_type(4))) float f32x4;
typedef __attribute__((ext_vector_type(2))) float f32x2;

__device__ __forceinline__ float sigmoidf_(float x) { return 1.f / (1.f + __expf(-x)); }

__device__ __forceinline__ unsigned short f2bf(float f) {
    __hip_bfloat16 h = __float2bfloat16(f);
    return *reinterpret_cast<unsigned short*>(&h);
}

__global__ void zero_kernel(float* p, int n) {
    int i = blockIdx.x * blockDim.x + threadIdx.x;
    if (i < n) p[i] = 0.f;
}

// ------------------------------------------------- param_gen stage 1: coefs
__global__ void param_coef_kernel(
    const float* __restrict__ h_time, const float* __restrict__ h_space,
    const float* __restrict__ Ttw, const float* __restrict__ Ttb,
    const float* __restrict__ wg_w1, const float* __restrict__ wg_b1,
    const float* __restrict__ wg_w2, const float* __restrict__ wg_b2,
    const float* __restrict__ bg_w1, const float* __restrict__ bg_b1,
    const float* __restrict__ bg_w2, const float* __restrict__ bg_b2,
    float* __restrict__ Coef)
{
    int blk = blockIdx.x;                 // g*(B*T) + b*T + c
    int g = blk / (B_ * T_);
    int rem = blk % (B_ * T_);
    int b = rem / T_, c = rem % T_;
    const float* h = (g < 2) ? h_time : h_space;
    int lane = threadIdx.x;

    __shared__ float mem2[64];
    __shared__ float m1s[64];

    {
        float s = 0.f;
        for (int l = 0; l < L_; ++l)
            s += tanhf(h[(b * L_ + l) * 64 + lane]) * Ttw[(g * T_ + c) * L_ + l];
        mem2[lane] = tanhf(s + Ttb[g * T_ + c]);
    }
    __syncthreads();
    {
        int j = lane & 31;
        bool isW = lane < 32;
        const float* w1 = isW ? wg_w1 : bg_w1;
        const float* b1 = isW ? wg_b1 : bg_b1;
        float s = b1[g * 32 + j];
        #pragma unroll 8
        for (int hh = 0; hh < 64; ++hh) s += mem2[hh] * w1[(g * 32 + j) * 64 + hh];
        m1s[lane] = fmaxf(s, 0.f);
    }
    __syncthreads();
    if (lane < 5 || (lane >= 8 && lane < 13)) {
        bool isW = lane < 5;
        int j = isW ? lane : lane - 8;
        const float* w2 = isW ? wg_w2 : bg_w2;
        const float* b2 = isW ? wg_b2 : bg_b2;
        int base = isW ? 0 : 32;
        float s = b2[g * 5 + j];
        #pragma unroll
        for (int k = 0; k < 32; ++k) s += m1s[base + k] * w2[(g * 5 + j) * 32 + k];
        Coef[blk * 16 + (isW ? j : 8 + j)] = fmaxf(s, 0.f);
    }
}

// ------------------------------------- param_gen stage 2: materialize W / B
#define WTOT (GBT_ * 4096)      // 1,703,936
#define BTOT (GBT_ * 64)        // 26,624
__global__ void param_mat_kernel(
    const float* __restrict__ wg_w3, const float* __restrict__ wg_b3,
    const float* __restrict__ bg_w3, const float* __restrict__ bg_b3,
    const float* __restrict__ Coef,
    float* __restrict__ Wg, float* __restrict__ Bg)
{
    int i = blockIdx.x * blockDim.x + threadIdx.x;
    if (i < WTOT) {
        int idx = i & 4095;              // = d*64+e
        int blk = i >> 12;
        int g = blk / (B_ * T_);
        const float* w3 = &wg_w3[((size_t)g * 4096 + idx) * 5];
        const float* cf = &Coef[blk * 16];
        Wg[i] = wg_b3[g * 4096 + idx]
              + cf[0]*w3[0] + cf[1]*w3[1] + cf[2]*w3[2] + cf[3]*w3[3] + cf[4]*w3[4];
    } else if (i < WTOT + BTOT) {
        int k = i - WTOT;
        int idx = k & 63;
        int blk = k >> 6;
        int g = blk / (B_ * T_);
        const float* w3 = &bg_w3[((size_t)g * 64 + idx) * 5];
        const float* cf = &Coef[blk * 16];
        Bg[k] = bg_b3[g * 64 + idx]
              + cf[8]*w3[0] + cf[9]*w3[1] + cf[10]*w3[2] + cf[11]*w3[3] + cf[12]*w3[4];
    }
}

// ----------------------------------------------- custom linear (MFMA bf16)
#define LCM_ROWS 64
#define XSTR 72
__global__ __launch_bounds__(256) void lincustom_t1_kernel(
    const float* __restrict__ x, const float* __restrict__ proxies,
    const float* __restrict__ out_prev,
    const float* __restrict__ W0, const float* __restrict__ Bi0,
    const float* __restrict__ W1, const float* __restrict__ Bi1,
    float* __restrict__ Y0, float* __restrict__ Y1, int cut_start, int cut_idx)
{
    int bt = blockIdx.x;  // b*T + t
    int b = bt / T_, t = bt % T_;
    int which = blockIdx.z;
    const float* W  = which ? W1 : W0;
    const float* Bi = which ? Bi1 : Bi0;
    float* Y        = which ? Y1 : Y0;

    __shared__ __align__(16) unsigned short wt[64 * XSTR];   // wt[e][k] = Wg[k*64+e]
    __shared__ __align__(16) unsigned short xs[LCM_ROWS * XSTR];
    __shared__ float bb[64];
    int tid = threadIdx.x;
    for (int i = tid; i < 4096; i += 256) {
        int d = i >> 6, e = i & 63;      // Wg layout [d*64+e]: d=in, e=out
        wt[e * XSTR + d] = f2bf(W[(size_t)bt * 4096 + i]);
    }
    int n0 = blockIdx.y * LCM_ROWS;
    if (t == 0) {
        const float* pp = proxies + (size_t)cut_idx * ND_;
        const float* op = out_prev + (size_t)b * ND_;
        for (int i = tid; i < LCM_ROWS * 64; i += 256) {
            int r = i >> 6, d = i & 63;
            int n = n0 + r;
            float xv = (n < N_) ? (pp[n * 64 + d] + op[n * 64 + d]) : 0.f;
            xs[r * XSTR + d] = f2bf(xv);
        }
    } else {
        const float* xb = x + ((size_t)(b * L_ + cut_start + t - 1) * N_) * 64;
        for (int i = tid; i < LCM_ROWS * 64; i += 256) {
            int r = i >> 6, d = i & 63;
            int n = n0 + r;
            float xv = (n < N_) ? xb[n * 64 + d] : 0.f;
            xs[r * XSTR + d] = f2bf(xv);
        }
    }
    if (tid < 64) bb[tid] = Bi[bt * 64 + tid];
    __syncthreads();

    int lane = tid & 63;
    int wv = tid >> 6;          // wave 0..3
    int rowa = lane & 15;
    int kgrp = lane >> 4;
    int rbase = wv * 16;

    f32x4 acc0 = {0,0,0,0}, acc1 = {0,0,0,0}, acc2 = {0,0,0,0}, acc3 = {0,0,0,0};
    #pragma unroll
    for (int ks = 0; ks < 2; ++ks) {
        short8 af = *(const short8*)&xs[(rbase + rowa) * XSTR + ks * 32 + kgrp * 8];
        short8 bf0 = *(const short8*)&wt[(0 * 16 + rowa) * XSTR + ks * 32 + kgrp * 8];
        short8 bf1 = *(const short8*)&wt[(1 * 16 + rowa) * XSTR + ks * 32 + kgrp * 8];
        short8 bf2 = *(const short8*)&wt[(2 * 16 + rowa) * XSTR + ks * 32 + kgrp * 8];
        short8 bf3 = *(const short8*)&wt[(3 * 16 + rowa) * XSTR + ks * 32 + kgrp * 8];
        acc0 = __builtin_amdgcn_mfma_f32_16x16x32_bf16(af, bf0, acc0, 0, 0, 0);
        acc1 = __builtin_amdgcn_mfma_f32_16x16x32_bf16(af, bf1, acc1, 0, 0, 0);
        acc2 = __builtin_amdgcn_mfma_f32_16x16x32_bf16(af, bf2, acc2, 0, 0, 0);
        acc3 = __builtin_amdgcn_mfma_f32_16x16x32_bf16(af, bf3, acc3, 0, 0, 0);
    }
    #pragma unroll
    for (int j = 0; j < 4; ++j) {
        int rc = kgrp * 4 + j;
        int n = n0 + rbase + rc;
        if (n >= N_) continue;
        size_t base = (size_t)bt * ND_ + (size_t)n * 64;
        int col = rowa;
        Y[base + 0 * 16 + col] = acc0[j] + bb[0 * 16 + col];
        Y[base + 1 * 16 + col] = acc1[j] + bb[1 * 16 + col];
        Y[base + 2 * 16 + col] = acc2[j] + bb[2 * 16 + col];
        Y[base + 3 * 16 + col] = acc3[j] + bb[3 * 16 + col];
    }
}

__global__ __launch_bounds__(256) void lincustom_kernel(
    const float* __restrict__ X,
    const float* __restrict__ W0, const float* __restrict__ Bi0,
    const float* __restrict__ W1, const float* __restrict__ Bi1,
    float* __restrict__ Y0, float* __restrict__ Y1)
{
    int bt = blockIdx.x;
    int which = blockIdx.z;
    const float* W  = which ? W1 : W0;
    const float* Bi = which ? Bi1 : Bi0;
    float* Y        = which ? Y1 : Y0;

    __shared__ __align__(16) unsigned short wt[64 * XSTR];
    __shared__ __align__(16) unsigned short xs[LCM_ROWS * XSTR];
    __shared__ float bb[64];
    int tid = threadIdx.x;
    for (int i = tid; i < 4096; i += 256) {
        int d = i >> 6, e = i & 63;      // Wg layout [d*64+e]
        wt[e * XSTR + d] = f2bf(W[(size_t)bt * 4096 + i]);
    }
    int n0 = blockIdx.y * LCM_ROWS;
    const float* xb = X + (size_t)bt * ND_;
    for (int i = tid; i < LCM_ROWS * 64; i += 256) {
        int r = i >> 6, d = i & 63;
        int n = n0 + r;
        float xv = (n < N_) ? xb[n * 64 + d] : 0.f;
        xs[r * XSTR + d] = f2bf(xv);
    }
    if (tid < 64) bb[tid] = Bi[bt * 64 + tid];
    __syncthreads();

    int lane = tid & 63;
    int wv = tid >> 6;
    int rowa = lane & 15;
    int kgrp = lane >> 4;
    int rbase = wv * 16;

    f32x4 acc0 = {0,0,0,0}, acc1 = {0,0,0,0}, acc2 = {0,0,0,0}, acc3 = {0,0,0,0};
    #pragma unroll
    for (int ks = 0; ks < 2; ++ks) {
        short8 af = *(const short8*)&xs[(rbase + rowa) * XSTR + ks * 32 + kgrp * 8];
        short8 bf0 = *(const short8*)&wt[(0 * 16 + rowa) * XSTR + ks * 32 + kgrp * 8];
        short8 bf1 = *(const short8*)&wt[(1 * 16 + rowa) * XSTR + ks * 32 + kgrp * 8];
        short8 bf2 = *(const short8*)&wt[(2 * 16 + rowa) * XSTR + ks * 32 + kgrp * 8];
        short8 bf3 = *(const short8*)&wt[(3 * 16 + rowa) * XSTR + ks * 32 + kgrp * 8];
        acc0 = __builtin_amdgcn_mfma_f32_16x16x32_bf16(af, bf0, acc0, 0, 0, 0);
        acc1 = __builtin_amdgcn_mfma_f32_16x16x32_bf16(af, bf1, acc1, 0, 0, 0);
        acc2 = __builtin_amdgcn_mfma_f32_16x16x32_bf16(af, bf2, acc2, 0, 0, 0);
        acc3 = __builtin_amdgcn_mfma_f32_16x16x32_bf16(af, bf3, acc3, 0, 0, 0);
    }
    #pragma unroll
    for (int j = 0; j < 4; ++j) {
        int rc = kgrp * 4 + j;
        int n = n0 + rbase + rc;
        if (n >= N_) continue;
        size_t base = (size_t)bt * ND_ + (size_t)n * 64;
        int col = rowa;
        Y[base + 0 * 16 + col] = acc0[j] + bb[0 * 16 + col];
        Y[base + 1 * 16 + col] = acc1[j] + bb[1 * 16 + col];
        Y[base + 2 * 16 + col] = acc2[j] + bb[2 * 16 + col];
        Y[base + 3 * 16 + col] = acc3[j] + bb[3 * 16 + col];
    }
}

// ------------------------------------------------------- temporal attention
// Packed-fp32 form (same recipe as spatial, round 32): f32x2 ext-vectors for
// the q·k dot and weighted-V accumulation -> v_pk_fma_f32. Transcendental
// chain stays scalar. Dot association changes pairwise-then-horizontal
// (~1e-7 relative).
__global__ void temporal_att_kernel(
    const float* __restrict__ proxies, const float* __restrict__ out_prev,
    const float* __restrict__ klin, const float* __restrict__ vlin,
    const float* __restrict__ rate, float* __restrict__ xatt, int cut_idx)
{
    int i = blockIdx.x * blockDim.x + threadIdx.x;
    if (i >= B_ * N_ * KH * T_) return;
    int r = i % T_;
    int h = (i / T_) % KH;
    int n = (i / (T_ * KH)) % N_;
    int b = i / (T_ * KH * N_);

    float srate = sigmoidf_(rate[0]);
    const float rs8 = 0.35355339059327373f;  // 1/sqrt(8)

    f32x2 q2[4];
    {
        const float4* pp = (const float4*)(proxies + (size_t)cut_idx * ND_ + n * 64 + h * 8);
        const float4* op = (const float4*)(out_prev + (size_t)b * ND_ + n * 64 + h * 8);
        float4 pa = pp[0], pb = pp[1], oa = op[0], ob = op[1];
        q2[0] = (f32x2){pa.x + oa.x, pa.y + oa.y};
        q2[1] = (f32x2){pa.z + oa.z, pa.w + oa.w};
        q2[2] = (f32x2){pb.x + ob.x, pb.y + ob.y};
        q2[3] = (f32x2){pb.z + ob.z, pb.w + ob.w};
    }

    float dec = (float)(T_ - r);
    float p[T_], sum = 0.f;
    for (int t = 0; t < T_; ++t) {
        const float4* kp = (const float4*)(klin + ((size_t)(b * T_ + t)) * ND_ + n * 64 + h * 8);
        float4 ka = kp[0], kb = kp[1];
        f32x2 s2 = q2[0] * (f32x2){ka.x, ka.y};
        s2 += q2[1] * (f32x2){ka.z, ka.w};
        s2 += q2[2] * (f32x2){kb.x, kb.y};
        s2 += q2[3] * (f32x2){kb.z, kb.w};
        float s = s2[0] + s2[1];
        float sa = sigmoidf_(s * rs8);
        float sg = sigmoidf_(sa * srate * dec);
        float at = tanhf(sa / (1.f + sg));
        p[t] = __expf(at);
        sum += p[t];
    }
    float inv = 1.f / sum;
    f32x2 acc2[4] = {{0,0},{0,0},{0,0},{0,0}};
    for (int t = 0; t < T_; ++t) {
        float w = p[t] * inv;
        f32x2 w2 = {w, w};
        const float4* vp = (const float4*)(vlin + ((size_t)(b * T_ + t)) * ND_ + n * 64 + h * 8);
        float4 va = vp[0], vb = vp[1];
        acc2[0] += w2 * (f32x2){va.x, va.y};
        acc2[1] += w2 * (f32x2){va.z, va.w};
        acc2[2] += w2 * (f32x2){vb.x, vb.y};
        acc2[3] += w2 * (f32x2){vb.z, vb.w};
    }
    float* op = xatt + ((size_t)(b * T_ + r)) * ND_ + n * 64 + h * 8;
    float4* op4 = (float4*)op;
    op4[0] = make_float4(acc2[0][0], acc2[0][1], acc2[1][0], acc2[1][1]);
    op4[1] = make_float4(acc2[2][0], acc2[2][1], acc2[3][0], acc2[3][1]);
}

// ------------------- fused dense-dense (ta chain, MFMA bf16, 2 phases)
#define DG_ROWS 64
__global__ __launch_bounds__(256) void dense2_ta_kernel(
    const float* __restrict__ X,
    const float* __restrict__ W1, const float* __restrict__ b1,
    const float* __restrict__ W2, const float* __restrict__ b2,
    float* __restrict__ Y, int M)
{
    __shared__ __align__(16) unsigned short wt1[64 * XSTR], wt2[64 * XSTR];
    __shared__ __align__(16) unsigned short xs[DG_ROWS * XSTR];
    __shared__ __align__(16) unsigned short in2[DG_ROWS * XSTR];
    __shared__ float bbs[2][64];
    int tid = threadIdx.x;
    for (int i = tid; i < 4096; i += 256) {
        int e = i >> 6, d = i & 63;      // dense W[e*64+d]: e=out, d=in
        wt1[e * XSTR + d] = f2bf(W1[i]);
        wt2[e * XSTR + d] = f2bf(W2[i]);
    }
    if (tid < 64) { bbs[0][tid] = b1[tid]; bbs[1][tid] = b2[tid]; }
    int row0 = blockIdx.x * DG_ROWS;
    for (int i = tid; i < DG_ROWS * 64; i += 256) {
        int r = i >> 6, d = i & 63;
        int row = row0 + r;
        xs[r * XSTR + d] = f2bf((row < M) ? X[(size_t)row * 64 + d] : 0.f);
    }
    __syncthreads();

    int lane = tid & 63;
    int wv = tid >> 6;
    int rowa = lane & 15;
    int kgrp = lane >> 4;
    int rbase = wv * 16;

    // phase 1: tanh(X*W1.T + b1) -> in2
    {
        f32x4 a0 = {0,0,0,0}, a1 = {0,0,0,0}, a2 = {0,0,0,0}, a3 = {0,0,0,0};
        #pragma unroll
        for (int ks = 0; ks < 2; ++ks) {
            short8 af = *(const short8*)&xs[(rbase + rowa) * XSTR + ks*32 + kgrp*8];
            short8 b0 = *(const short8*)&wt1[(0*16 + rowa) * XSTR + ks*32 + kgrp*8];
            short8 b1f = *(const short8*)&wt1[(1*16 + rowa) * XSTR + ks*32 + kgrp*8];
            short8 b2f = *(const short8*)&wt1[(2*16 + rowa) * XSTR + ks*32 + kgrp*8];
            short8 b3f = *(const short8*)&wt1[(3*16 + rowa) * XSTR + ks*32 + kgrp*8];
            a0 = __builtin_amdgcn_mfma_f32_16x16x32_bf16(af, b0, a0, 0, 0, 0);
            a1 = __builtin_amdgcn_mfma_f32_16x16x32_bf16(af, b1f, a1, 0, 0, 0);
            a2 = __builtin_amdgcn_mfma_f32_16x16x32_bf16(af, b2f, a2, 0, 0, 0);
            a3 = __builtin_amdgcn_mfma_f32_16x16x32_bf16(af, b3f, a3, 0, 0, 0);
        }
        #pragma unroll
        for (int j = 0; j < 4; ++j) {
            int rr = rbase + kgrp * 4 + j;
            in2[rr * XSTR + 0*16 + rowa] = f2bf(tanhf(a0[j] + bbs[0][0*16 + rowa]));
            in2[rr * XSTR + 1*16 + rowa] = f2bf(tanhf(a1[j] + bbs[0][1*16 + rowa]));
            in2[rr * XSTR + 2*16 + rowa] = f2bf(tanhf(a2[j] + bbs[0][2*16 + rowa]));
            in2[rr * XSTR + 3*16 + rowa] = f2bf(tanhf(a3[j] + bbs[0][3*16 + rowa]));
        }
    }
    __syncthreads();

    // phase 2: Y = in2*W2.T + b2 -> fp32 global
    {
        f32x4 a0 = {0,0,0,0}, a1 = {0,0,0,0}, a2 = {0,0,0,0}, a3 = {0,0,0,0};
        #pragma unroll
        for (int ks = 0; ks < 2; ++ks) {
            short8 af = *(const short8*)&in2[(rbase + rowa) * XSTR + ks*32 + kgrp*8];
            short8 b0 = *(const short8*)&wt2[(0*16 + rowa) * XSTR + ks*32 + kgrp*8];
            short8 b1f = *(const short8*)&wt2[(1*16 + rowa) * XSTR + ks*32 + kgrp*8];
            short8 b2f = *(const short8*)&wt2[(2*16 + rowa) * XSTR + ks*32 + kgrp*8];
            short8 b3f = *(const short8*)&wt2[(3*16 + rowa) * XSTR + ks*32 + kgrp*8];
            a0 = __builtin_amdgcn_mfma_f32_16x16x32_bf16(af, b0, a0, 0, 0, 0);
            a1 = __builtin_amdgcn_mfma_f32_16x16x32_bf16(af, b1f, a1, 0, 0, 0);
            a2 = __builtin_amdgcn_mfma_f32_16x16x32_bf16(af, b2f, a2, 0, 0, 0);
            a3 = __builtin_amdgcn_mfma_f32_16x16x32_bf16(af, b3f, a3, 0, 0, 0);
        }
        #pragma unroll
        for (int j = 0; j < 4; ++j) {
            int rr = rbase + kgrp * 4 + j;
            int row = row0 + rr;
            if (row >= M) continue;
            size_t base = (size_t)row * 64;
            Y[base + 0*16 + rowa] = a0[j] + bbs[1][0*16 + rowa];
            Y[base + 1*16 + rowa] = a1[j] + bbs[1][1*16 + rowa];
            Y[base + 2*16 + rowa] = a2[j] + bbs[1][2*16 + rowa];
            Y[base + 3*16 + rowa] = a3[j] + bbs[1][3*16 + rowa];
        }
    }
}

// ------------------------- fused gate chain (4 dense layers, MFMA bf16)
__global__ __launch_bounds__(256) void dense2_gate_kernel(
    const float* __restrict__ X,
    const float* __restrict__ Wsa1, const float* __restrict__ bsa1,
    const float* __restrict__ Wsa2, const float* __restrict__ bsa2,
    const float* __restrict__ Wag1, const float* __restrict__ bag1,
    const float* __restrict__ Wag2, const float* __restrict__ bag2,
    float* __restrict__ OG, int M)
{
    __shared__ __align__(16) unsigned short wt1[64 * XSTR], wt2[64 * XSTR],
                                            wt3[64 * XSTR], wt4[64 * XSTR];
    __shared__ __align__(16) unsigned short xs[DG_ROWS * XSTR];
    __shared__ __align__(16) unsigned short in2[DG_ROWS * XSTR];
    __shared__ float bbs[4][64];
    int tid = threadIdx.x;
    for (int i = tid; i < 4096; i += 256) {
        int e = i >> 6, d = i & 63;      // W[e*64+d]: e=out, d=in
        wt1[e * XSTR + d] = f2bf(Wsa1[i]);
        wt2[e * XSTR + d] = f2bf(Wsa2[i]);
        wt3[e * XSTR + d] = f2bf(Wag1[i]);
        wt4[e * XSTR + d] = f2bf(Wag2[i]);
    }
    if (tid < 64) {
        bbs[0][tid] = bsa1[tid]; bbs[1][tid] = bsa2[tid];
        bbs[2][tid] = bag1[tid]; bbs[3][tid] = bag2[tid];
    }
    int row0 = blockIdx.x * DG_ROWS;
    for (int i = tid; i < DG_ROWS * 64; i += 256) {
        int r = i >> 6, d = i & 63;
        int row = row0 + r;
        xs[r * XSTR + d] = f2bf((row < M) ? X[(size_t)row * 64 + d] : 0.f);
    }
    __syncthreads();

    int lane = tid & 63;
    int wv = tid >> 6;
    int rowa = lane & 15;
    int kgrp = lane >> 4;
    int rbase = wv * 16;

#define DG_PHASE(WT, BIDX, ACTEXPR, DST)                                         \
    {                                                                            \
        f32x4 a0 = {0,0,0,0}, a1 = {0,0,0,0}, a2 = {0,0,0,0}, a3 = {0,0,0,0};    \
        _Pragma("unroll")                                                        \
        for (int ks = 0; ks < 2; ++ks) {                                         \
            short8 af = *(const short8*)&SRC[(rbase + rowa) * XSTR + ks*32 + kgrp*8]; \
            short8 b0 = *(const short8*)&WT[(0*16 + rowa) * XSTR + ks*32 + kgrp*8];   \
            short8 b1 = *(const short8*)&WT[(1*16 + rowa) * XSTR + ks*32 + kgrp*8];   \
            short8 b2 = *(const short8*)&WT[(2*16 + rowa) * XSTR + ks*32 + kgrp*8];   \
            short8 b3 = *(const short8*)&WT[(3*16 + rowa) * XSTR + ks*32 + kgrp*8];   \
            a0 = __builtin_amdgcn_mfma_f32_16x16x32_bf16(af, b0, a0, 0, 0, 0);   \
            a1 = __builtin_amdgcn_mfma_f32_16x16x32_bf16(af, b1, a1, 0, 0, 0);   \
            a2 = __builtin_amdgcn_mfma_f32_16x16x32_bf16(af, b2, a2, 0, 0, 0);   \
            a3 = __builtin_amdgcn_mfma_f32_16x16x32_bf16(af, b3, a3, 0, 0, 0);   \
        }                                                                        \
        _Pragma("unroll")                                                        \
        for (int j = 0; j < 4; ++j) {                                            \
            int rr = rbase + kgrp * 4 + j;                                       \
            float v0 = a0[j] + bbs[BIDX][0*16 + rowa];                           \
            float v1 = a1[j] + bbs[BIDX][1*16 + rowa];                           \
            float v2 = a2[j] + bbs[BIDX][2*16 + rowa];                           \
            float v3 = a3[j] + bbs[BIDX][3*16 + rowa];                           \
            ACTEXPR;                                                             \
            DST[rr * XSTR + 0*16 + rowa] = f2bf(v0);                             \
            DST[rr * XSTR + 1*16 + rowa] = f2bf(v1);                             \
            DST[rr * XSTR + 2*16 + rowa] = f2bf(v2);                             \
            DST[rr * XSTR + 3*16 + rowa] = f2bf(v3);                             \
        }                                                                        \
    }

    // phase 1: relu(X*W1 + b1) -> in2
#define SRC xs
    DG_PHASE(wt1, 0,
        { v0 = fmaxf(v0, 0.f); v1 = fmaxf(v1, 0.f); v2 = fmaxf(v2, 0.f); v3 = fmaxf(v3, 0.f); },
        in2)
#undef SRC
    __syncthreads();

    // phase 2: o = in2*W2 + b2 -> keep fp32 oreg, write bf16 to xs
    float og0[4], og1[4], og2[4], og3[4];
    {
        f32x4 a0 = {0,0,0,0}, a1 = {0,0,0,0}, a2 = {0,0,0,0}, a3 = {0,0,0,0};
        #pragma unroll
        for (int ks = 0; ks < 2; ++ks) {
            short8 af = *(const short8*)&in2[(rbase + rowa) * XSTR + ks*32 + kgrp*8];
            short8 b0 = *(const short8*)&wt2[(0*16 + rowa) * XSTR + ks*32 + kgrp*8];
            short8 b1 = *(const short8*)&wt2[(1*16 + rowa) * XSTR + ks*32 + kgrp*8];
            short8 b2 = *(const short8*)&wt2[(2*16 + rowa) * XSTR + ks*32 + kgrp*8];
            short8 b3 = *(const short8*)&wt2[(3*16 + rowa) * XSTR + ks*32 + kgrp*8];
            a0 = __builtin_amdgcn_mfma_f32_16x16x32_bf16(af, b0, a0, 0, 0, 0);
            a1 = __builtin_amdgcn_mfma_f32_16x16x32_bf16(af, b1, a1, 0, 0, 0);
            a2 = __builtin_amdgcn_mfma_f32_16x16x32_bf16(af, b2, a2, 0, 0, 0);
            a3 = __builtin_amdgcn_mfma_f32_16x16x32_bf16(af, b3, a3, 0, 0, 0);
        }
        __syncthreads();   // all phase-1 reads done before xs overwrite
        #pragma unroll
        for (int j = 0; j < 4; ++j) {
            int rr = rbase + kgrp * 4 + j;
            og0[j] = a0[j] + bbs[1][0*16 + rowa];
            og1[j] = a1[j] + bbs[1][1*16 + rowa];
            og2[j] = a2[j] + bbs[1][2*16 + rowa];
            og3[j] = a3[j] + bbs[1][3*16 + rowa];
            xs[rr * XSTR + 0*16 + rowa] = f2bf(og0[j]);
            xs[rr * XSTR + 1*16 + rowa] = f2bf(og1[j]);
            xs[rr * XSTR + 2*16 + rowa] = f2bf(og2[j]);
            xs[rr * XSTR + 3*16 + rowa] = f2bf(og3[j]);
        }
    }
    __syncthreads();

    // phase 3: relu(o*W3 + b3) -> in2
#define SRC xs
    DG_PHASE(wt3, 2,
        { v0 = fmaxf(v0, 0.f); v1 = fmaxf(v1, 0.f); v2 = fmaxf(v2, 0.f); v3 = fmaxf(v3, 0.f); },
        in2)
#undef SRC
    __syncthreads();

    // phase 4: gate = in2*W4 + b4; og = o * sigmoid(gate) -> global
    {
        f32x4 a0 = {0,0,0,0}, a1 = {0,0,0,0}, a2 = {0,0,0,0}, a3 = {0,0,0,0};
        #pragma unroll
        for (int ks = 0; ks < 2; ++ks) {
            short8 af = *(const short8*)&in2[(rbase + rowa) * XSTR + ks*32 + kgrp*8];
            short8 b0 = *(const short8*)&wt4[(0*16 + rowa) * XSTR + ks*32 + kgrp*8];
            short8 b1 = *(const short8*)&wt4[(1*16 + rowa) * XSTR + ks*32 + kgrp*8];
            short8 b2 = *(const short8*)&wt4[(2*16 + rowa) * XSTR + ks*32 + kgrp*8];
            short8 b3 = *(const short8*)&wt4[(3*16 + rowa) * XSTR + ks*32 + kgrp*8];
            a0 = __builtin_amdgcn_mfma_f32_16x16x32_bf16(af, b0, a0, 0, 0, 0);
            a1 = __builtin_amdgcn_mfma_f32_16x16x32_bf16(af, b1, a1, 0, 0, 0);
            a2 = __builtin_amdgcn_mfma_f32_16x16x32_bf16(af, b2, a2, 0, 0, 0);
            a3 = __builtin_amdgcn_mfma_f32_16x16x32_bf16(af, b3, a3, 0, 0, 0);
        }
        #pragma unroll
        for (int j = 0; j < 4; ++j) {
            int rr = rbase + kgrp * 4 + j;
            int row = row0 + rr;
            if (row >= M) continue;
            size_t base = (size_t)row * 64;
            OG[base + 0*16 + rowa] = og0[j] * sigmoidf_(a0[j] + bbs[3][0*16 + rowa]);
            OG[base + 1*16 + rowa] = og1[j] * sigmoidf_(a1[j] + bbs[3][1*16 + rowa]);
            OG[base + 2*16 + rowa] = og2[j] * sigmoidf_(a2[j] + bbs[3][2*16 + rowa]);
            OG[base + 3*16 + rowa] = og3[j] * sigmoidf_(a3[j] + bbs[3][3*16 + rowa]);
        }
    }
#undef DG_PHASE
}

// -------------------------------------------------------- spatial attention
// Packed-fp32 form (round-32 verified): f32x2 -> v_pk_fma_f32.
__global__ void spatial_att_kernel(const float* __restrict__ Yq,
                                   const float* __restrict__ Ks, const float* __restrict__ Vs,
                                   float* __restrict__ Out)
{
    int blk = blockIdx.x;
    int bt = blk % (B_ * T_);
    int h = blk / (B_ * T_);
    __shared__ float4 kl[N_ * 2], vl[N_ * 2];
    int tid = threadIdx.x;
    for (int i = tid; i < N_ * 2; i += blockDim.x) {
        int m = i >> 1, half = i & 1;
        kl[i] = *(const float4*)&Ks[(size_t)bt * ND_ + m * 64 + h * 8 + half * 4];
        vl[i] = *(const float4*)&Vs[(size_t)bt * ND_ + m * 64 + h * 8 + half * 4];
    }
    __syncthreads();
    const float rs8 = 0.35355339059327373f;
    for (int n = tid; n < N_; n += blockDim.x) {
        f32x2 q2[4];
        const float* qp = Yq + (size_t)bt * ND_ + n * 64 + h * 8;
        #pragma unroll
        for (int j = 0; j < 4; ++j) {
            q2[j][0] = qp[2 * j] * rs8;
            q2[j][1] = qp[2 * j + 1] * rs8;
        }
        float sum = 0.f;
        f32x2 acc2[4] = {{0,0},{0,0},{0,0},{0,0}};
        for (int m = 0; m < N_; ++m) {
            float4 ka = kl[2 * m], kb = kl[2 * m + 1];
            f32x2 s2 = q2[0] * (f32x2){ka.x, ka.y};
            s2 += q2[1] * (f32x2){ka.z, ka.w};
            s2 += q2[2] * (f32x2){kb.x, kb.y};
            s2 += q2[3] * (f32x2){kb.z, kb.w};
            float p = __expf(s2[0] + s2[1]);
            sum += p;
            f32x2 p2 = {p, p};
            float4 va = vl[2 * m], vb = vl[2 * m + 1];
            acc2[0] += p2 * (f32x2){va.x, va.y};
            acc2[1] += p2 * (f32x2){va.z, va.w};
            acc2[2] += p2 * (f32x2){vb.x, vb.y};
            acc2[3] += p2 * (f32x2){vb.z, vb.w};
        }
        float inv = 1.f / sum;
        float* op = Out + (size_t)bt * ND_ + n * 64 + h * 8;
        #pragma unroll
        for (int j = 0; j < 4; ++j) {
            op[2 * j]     = acc2[j][0] * inv;
            op[2 * j + 1] = acc2[j][1] * inv;
        }
    }
}

// ------------------------------------------------------------- gate reduce
__global__ void gate_reduce_kernel(const float* __restrict__ OG,
                                   float* __restrict__ out_fp32, float* __restrict__ d_out,
                                   int cut_idx)
{
    int i = blockIdx.x * blockDim.x + threadIdx.x;
    if (i >= B_ * ND_) return;
    int b = i / ND_;
    int nd = i % ND_;
    float s = 0.f;
    for (int t = 0; t < T_; ++t)
        s += OG[((size_t)(b * T_ + t)) * ND_ + nd];
    out_fp32[i] = s;
    d_out[((size_t)b * CUTS_ + cut_idx) * ND_ + nd] = s;
}

// ======================================================================
extern "C" void kernel_launch(void* const* d_in, const int* in_sizes, int n_in,
                              void* d_out, int out_size, void* d_ws, size_t ws_size,
                              hipStream_t stream)
{
    const float* x        = (const float*)d_in[0];
    const float* h_time   = (const float*)d_in[1];
    const float* h_space  = (const float*)d_in[2];
    const float* gen_Tt_w = (const float*)d_in[3];
    const float* gen_Tt_b = (const float*)d_in[4];
    const float* wg_w1    = (const float*)d_in[5];
    const float* wg_b1    = (const float*)d_in[6];
    const float* wg_w2    = (const float*)d_in[7];
    const float* wg_b2    = (const float*)d_in[8];
    const float* wg_w3    = (const float*)d_in[9];
    const float* wg_b3    = (const float*)d_in[10];
    const float* bg_w1    = (const float*)d_in[11];
    const float* bg_b1    = (const float*)d_in[12];
    const float* bg_w2    = (const float*)d_in[13];
    const float* bg_b2    = (const float*)d_in[14];
    const float* bg_w3    = (const float*)d_in[15];
    const float* bg_b3    = (const float*)d_in[16];
    const float* proxies  = (const float*)d_in[17];
    const float* ta_p1_w  = (const float*)d_in[18];
    const float* ta_p1_b  = (const float*)d_in[19];
    const float* ta_p2_w  = (const float*)d_in[20];
    const float* ta_p2_b  = (const float*)d_in[21];
    const float* rate     = (const float*)d_in[22];
    const float* sa_p1_w  = (const float*)d_in[23];
    const float* sa_p1_b  = (const float*)d_in[24];
    const float* sa_p2_w  = (const float*)d_in[25];
    const float* sa_p2_b  = (const float*)d_in[26];
    const float* agg_w1   = (const float*)d_in[27];
    const float* agg_b1   = (const float*)d_in[28];
    const float* agg_w2   = (const float*)d_in[29];
    const float* agg_b2   = (const float*)d_in[30];

    float* outp = (float*)d_out;

    float* ws = (float*)d_ws;
    const size_t S = (size_t)B_ * TND_;             // 1,378,944 floats
    const size_t genW = (size_t)B_ * T_ * 4096;
    const size_t genB = (size_t)B_ * T_ * 64;
    size_t off = 0;
    float* Wg   = ws + off; off += 4 * genW;
    float* Bg   = ws + off; off += 4 * genB;
    float* A    = ws + off; off += S;
    float* Bb   = ws + off; off += S;
    float* C    = ws + off; off += S;
    float* Dd   = ws + off; off += S;
    float* out_fp32 = ws + off; off += (size_t)B_ * ND_;
    float* Coef = ws + off; off += GBT_ * 16;

    zero_kernel<<<(B_ * ND_ + 255) / 256, 256, 0, stream>>>(out_fp32, B_ * ND_);

    param_coef_kernel<<<GBT_, 64, 0, stream>>>(
        h_time, h_space, gen_Tt_w, gen_Tt_b,
        wg_w1, wg_b1, wg_w2, wg_b2,
        bg_w1, bg_b1, bg_w2, bg_b2, Coef);
    param_mat_kernel<<<(WTOT + BTOT + 255) / 256, 256, 0, stream>>>(
        wg_w3, wg_b3, bg_w3, bg_b3, Coef, Wg, Bg);

    const int cut_starts[4] = {0, 12, 24, 36};
    const dim3 lcGrid(B_ * T_, (N_ + LCM_ROWS - 1) / LCM_ROWS, 2);  // (104, 4, 2)
    const int dgGrid = (M_ + DG_ROWS - 1) / DG_ROWS;  // 337
    const int taGrid = (B_ * N_ * KH * T_ + 255) / 256;

    for (int cut = 0; cut < CUTS_; ++cut) {
        // temporal k (gen0) -> A, v (gen1) -> Bb, from virtual t1
        lincustom_t1_kernel<<<lcGrid, 256, 0, stream>>>(
            x, proxies, out_fp32,
            Wg + 0 * genW, Bg + 0 * genB, Wg + 1 * genW, Bg + 1 * genB,
            A, Bb, cut_starts[cut], cut);
        // temporal attention -> C  (packed-math)
        temporal_att_kernel<<<taGrid, 256, 0, stream>>>(
            proxies, out_fp32, A, Bb, rate, C, cut);
        // y = dense(tanh(dense(xatt, p1)), p2) -> Dd  (MFMA)
        dense2_ta_kernel<<<dgGrid, 256, 0, stream>>>(C, ta_p1_w, ta_p1_b, ta_p2_w, ta_p2_b, Dd, M_);
        // spatial k (gen2) -> A, v (gen3) -> Bb
        lincustom_kernel<<<lcGrid, 256, 0, stream>>>(
            Dd, Wg + 2 * genW, Bg + 2 * genB, Wg + 3 * genW, Bg + 3 * genB, A, Bb);
        // spatial attention (q = Dd) -> C  (fp32, packed-math)
        spatial_att_kernel<<<B_ * T_ * KH, 256, 0, stream>>>(Dd, A, Bb, C);
        // fused: o = dense2(sa chain), og = o*sigmoid(dense2(agg chain)) -> Dd
        dense2_gate_kernel<<<dgGrid, 256, 0, stream>>>(
            C, sa_p1_w, sa_p1_b, sa_p2_w, sa_p2_b,
            agg_w1, agg_b1, agg_w2, agg_b2, Dd, M_);
        // out = sum_t og
        gate_reduce_kernel<<<(B_ * ND_ + 255) / 256, 256, 0, stream>>>(
            Dd, out_fp32, outp, cut);
    }
}